// Round 1
// baseline (700.249 us; speedup 1.0000x reference)
//
#include <hip/hip_runtime.h>
#include <hip/hip_bf16.h>
#include <cstdint>

// ---------------------------------------------------------------------------
// HGAT: 2-layer hetero GAT (user<->movie), H=4 heads, C=32, HC=128, fp32.
// Pipeline per conv:  hs = x_src @ Wsrc (GEMM);  a_s = x_src @ vs;  a_d = x_dst @ vd
//   (vs/vd fold the per-head attention dot into a [K,4] matrix)
// then one CSR edge pass per dst node:
//   out[d] = (sum_e exp(lrelu(a_s[src]+a_d[d])) * hs[src]) / (sum_e w) + b ; lrelu(0.01)
// Softmax max-subtraction skipped (logits bounded ~|e|<1 -> no overflow; shift-invariant).
// ---------------------------------------------------------------------------

#define HC 128   // H*C
#define HH 4     // heads

// ---------------- small precompute: v[k,h] = sum_c W[k,h*32+c]*a[h,c] -------
__global__ void make_v_k(const float* __restrict__ W, const float* __restrict__ a,
                         float* __restrict__ v, int K) {
    int gid = blockIdx.x * 256 + threadIdx.x;
    if (gid >= K * HH) return;
    int k = gid >> 2, h = gid & 3;
    const float* wr = W + (size_t)k * HC + h * 32;
    const float* ar = a + h * 32;
    float s = 0.f;
    #pragma unroll
    for (int c = 0; c < 32; ++c) s = fmaf(wr[c], ar[c], s);
    v[k * HH + h] = s;
}

// ---------------- per-node attention terms: att[n,h] = x[row] . v[:,h] ------
__global__ __launch_bounds__(256) void node_att_k(
    const float* __restrict__ x, const int* __restrict__ idx,
    const float* __restrict__ v, float* __restrict__ att, int n, int K) {
    int wave = (int)((blockIdx.x * 256u + threadIdx.x) >> 6);
    int lane = threadIdx.x & 63;
    if (wave >= n) return;                       // uniform per wave
    int row = idx ? idx[wave] : wave;
    const float* xr = x + (size_t)row * K;
    float4 acc = make_float4(0.f, 0.f, 0.f, 0.f);
    for (int k = lane; k < K; k += 64) {
        float xv = xr[k];
        float4 vv = reinterpret_cast<const float4*>(v)[k];
        acc.x = fmaf(xv, vv.x, acc.x);
        acc.y = fmaf(xv, vv.y, acc.y);
        acc.z = fmaf(xv, vv.z, acc.z);
        acc.w = fmaf(xv, vv.w, acc.w);
    }
    #pragma unroll
    for (int off = 32; off; off >>= 1) {
        acc.x += __shfl_down(acc.x, off);
        acc.y += __shfl_down(acc.y, off);
        acc.z += __shfl_down(acc.z, off);
        acc.w += __shfl_down(acc.w, off);
    }
    if (lane == 0) reinterpret_cast<float4*>(att)[wave] = acc;
}

// ---------------- fp32 tiled GEMM: C[M,BN] = gather(A)[M,K] @ B[K,BN] (+bias)
template <int BN>
__global__ __launch_bounds__(256) void gemm_f32(
    const float* __restrict__ A, const int* __restrict__ aidx,
    const float* __restrict__ B, const float* __restrict__ bias,
    float* __restrict__ C, int M, int K) {
    constexpr int BM = 128, BK = 32;
    constexpr int TN = BN / 16;                  // 8 (BN=128) or 4 (BN=64)
    __shared__ __align__(16) float As[BK][BM + 4];   // transposed A tile
    __shared__ __align__(16) float Bs[BK][BN + 4];
    int tid = threadIdx.x;
    int tx = tid & 15, ty = tid >> 4;
    int m0 = blockIdx.x * BM;
    int row0 = ty * 8;
    int col0 = tx * TN;

    float acc[8][TN] = {};
    for (int kc = 0; kc < K; kc += BK) {
        // A tile: BM*BK floats via float4, store transposed
        for (int v = tid; v < BM * BK / 4; v += 256) {
            int ar = v >> 3;                     // BK/4 = 8 vec4 per row
            int ac4 = v & 7;
            float4 a4 = make_float4(0.f, 0.f, 0.f, 0.f);
            int grow = m0 + ar;
            if (grow < M) {
                int arow = aidx ? aidx[grow] : grow;
                a4 = *reinterpret_cast<const float4*>(&A[(size_t)arow * K + kc + ac4 * 4]);
            }
            As[ac4 * 4 + 0][ar] = a4.x;
            As[ac4 * 4 + 1][ar] = a4.y;
            As[ac4 * 4 + 2][ar] = a4.z;
            As[ac4 * 4 + 3][ar] = a4.w;
        }
        // B tile: BK*BN floats via float4 (B is [K,BN], dense)
        for (int v = tid; v < BK * BN / 4; v += 256) {
            int br = v / (BN / 4);
            int bc4 = v % (BN / 4);
            *reinterpret_cast<float4*>(&Bs[br][bc4 * 4]) =
                *reinterpret_cast<const float4*>(&B[(size_t)(kc + br) * BN + bc4 * 4]);
        }
        __syncthreads();
        #pragma unroll 4
        for (int kk = 0; kk < BK; ++kk) {
            float a[8];
            *reinterpret_cast<float4*>(&a[0]) = *reinterpret_cast<const float4*>(&As[kk][row0]);
            *reinterpret_cast<float4*>(&a[4]) = *reinterpret_cast<const float4*>(&As[kk][row0 + 4]);
            float b[TN];
            #pragma unroll
            for (int j = 0; j < TN; j += 4)
                *reinterpret_cast<float4*>(&b[j]) = *reinterpret_cast<const float4*>(&Bs[kk][col0 + j]);
            #pragma unroll
            for (int i = 0; i < 8; ++i)
                #pragma unroll
                for (int j = 0; j < TN; ++j)
                    acc[i][j] = fmaf(a[i], b[j], acc[i][j]);
        }
        __syncthreads();
    }
    float bv[TN];
    #pragma unroll
    for (int j = 0; j < TN; ++j) bv[j] = bias ? bias[col0 + j] : 0.f;
    #pragma unroll
    for (int i = 0; i < 8; ++i) {
        int gr = m0 + row0 + i;
        if (gr < M) {
            #pragma unroll
            for (int j = 0; j < TN; j += 4) {
                float4 o = make_float4(acc[i][j] + bv[j], acc[i][j + 1] + bv[j + 1],
                                       acc[i][j + 2] + bv[j + 2], acc[i][j + 3] + bv[j + 3]);
                *reinterpret_cast<float4*>(&C[(size_t)gr * BN + col0 + j]) = o;
            }
        }
    }
}

// ---------------- CSR build ------------------------------------------------
__global__ void hist_k(const int* __restrict__ dst, int* __restrict__ deg, int E) {
    int e = blockIdx.x * 256 + threadIdx.x;
    if (e < E) atomicAdd(&deg[dst[e]], 1);
}

__global__ void scan_block_k(const int* __restrict__ deg, int n, int len,
                             int* __restrict__ out, int* __restrict__ partial) {
    __shared__ int s[256];
    int i = blockIdx.x * 256 + threadIdx.x;
    int v = (i < n) ? deg[i] : 0;
    s[threadIdx.x] = v;
    __syncthreads();
    for (int off = 1; off < 256; off <<= 1) {
        int t = (threadIdx.x >= off) ? s[threadIdx.x - off] : 0;
        __syncthreads();
        s[threadIdx.x] += t;
        __syncthreads();
    }
    if (i < len) out[i] = s[threadIdx.x] - v;    // exclusive within block
    if (threadIdx.x == 255) partial[blockIdx.x] = s[255];
}

__global__ void scan_partial_k(int* __restrict__ partial, int nb) {
    __shared__ int s[512];
    int t = threadIdx.x;
    int v = (t < nb) ? partial[t] : 0;
    s[t] = v;
    __syncthreads();
    for (int off = 1; off < 512; off <<= 1) {
        int x = (t >= off) ? s[t - off] : 0;
        __syncthreads();
        s[t] += x;
        __syncthreads();
    }
    if (t < nb) partial[t] = s[t] - v;           // exclusive
}

__global__ void add_off_k(int* __restrict__ out, const int* __restrict__ partial, int len) {
    int i = blockIdx.x * 256 + threadIdx.x;
    if (i < len) out[i] += partial[i >> 8];
}

__global__ void fill_k(const int* __restrict__ src, const int* __restrict__ dst,
                       const int* __restrict__ rs, int* __restrict__ cnt,
                       int* __restrict__ csr_src, int E) {
    int e = blockIdx.x * 256 + threadIdx.x;
    if (e < E) {
        int d = dst[e];
        int pos = rs[d] + atomicAdd(&cnt[d], 1);
        csr_src[pos] = src[e];
    }
}

// ---------------- per-dst aggregation (one block = one node) ----------------
// block 256 = 8 edge-slots x 32 float4-channel lanes
__global__ __launch_bounds__(256) void agg_k(
    const int* __restrict__ rs, const int* __restrict__ csr_src,
    const float* __restrict__ a_s, const float* __restrict__ a_d,
    const float* __restrict__ hs, const float* __restrict__ bias,
    float* __restrict__ out, int n) {
    __shared__ __align__(16) float4 sh_acc[256];
    __shared__ float sh_w[256];
    int node = blockIdx.x;
    int tid = threadIdx.x;
    int slot = tid >> 5;
    int c = tid & 31;        // float4 group: channels 4c..4c+3
    int h = c >> 3;          // head
    float ad = a_d[node * HH + h];
    int s0 = rs[node], s1 = rs[node + 1];
    float4 acc = make_float4(0.f, 0.f, 0.f, 0.f);
    float wsum = 0.f;
    for (int i = s0 + slot; i < s1; i += 8) {
        int src = csr_src[i];
        float e = a_s[src * HH + h] + ad;
        e = e > 0.f ? e : 0.2f * e;
        float w = __expf(e);
        wsum += w;
        float4 hv = reinterpret_cast<const float4*>(hs)[(size_t)src * 32 + c];
        acc.x = fmaf(w, hv.x, acc.x);
        acc.y = fmaf(w, hv.y, acc.y);
        acc.z = fmaf(w, hv.z, acc.z);
        acc.w = fmaf(w, hv.w, acc.w);
    }
    sh_acc[tid] = acc;
    sh_w[tid] = wsum;
    __syncthreads();
    if (slot == 0) {
        #pragma unroll
        for (int s2 = 1; s2 < 8; ++s2) {
            float4 o = sh_acc[s2 * 32 + c];
            acc.x += o.x; acc.y += o.y; acc.z += o.z; acc.w += o.w;
            wsum += sh_w[s2 * 32 + c];
        }
        float inv = 1.f / (wsum + 1e-16f);
        float4 b4 = reinterpret_cast<const float4*>(bias)[c];
        float4 v;
        v.x = fmaf(acc.x, inv, b4.x);
        v.y = fmaf(acc.y, inv, b4.y);
        v.z = fmaf(acc.z, inv, b4.z);
        v.w = fmaf(acc.w, inv, b4.w);
        v.x = v.x > 0.f ? v.x : 0.01f * v.x;
        v.y = v.y > 0.f ? v.y : 0.01f * v.y;
        v.z = v.z > 0.f ? v.z : 0.01f * v.z;
        v.w = v.w > 0.f ? v.w : 0.01f * v.w;
        reinterpret_cast<float4*>(out)[(size_t)node * 32 + c] = v;
    }
}

// ---------------------------------------------------------------------------
extern "C" void kernel_launch(void* const* d_in, const int* in_sizes, int n_in,
                              void* d_out, int out_size, void* d_ws, size_t ws_size,
                              hipStream_t stream) {
    const int Nu = in_sizes[0];
    const int Nm = in_sizes[1];
    const int E1 = in_sizes[2];   // um edges
    const int E2 = in_sizes[4];   // mu edges
    const int D  = in_sizes[6] / Nu;   // 64
    const int O  = in_sizes[27];       // 64

    const int*   user_ids  = (const int*)d_in[0];
    const int*   movie_ids = (const int*)d_in[1];
    const int*   um_src    = (const int*)d_in[2];
    const int*   um_dst    = (const int*)d_in[3];
    const int*   mu_src    = (const int*)d_in[4];
    const int*   mu_dst    = (const int*)d_in[5];
    const float* user_emb  = (const float*)d_in[6];
    const float* movie_emb = (const float*)d_in[7];
    const float* l1_um_Wsrc = (const float*)d_in[8];
    const float* l1_um_Wdst = (const float*)d_in[9];
    const float* l1_um_asrc = (const float*)d_in[10];
    const float* l1_um_adst = (const float*)d_in[11];
    const float* l1_um_b    = (const float*)d_in[12];
    const float* l1_mu_Wsrc = (const float*)d_in[13];
    const float* l1_mu_Wdst = (const float*)d_in[14];
    const float* l1_mu_asrc = (const float*)d_in[15];
    const float* l1_mu_adst = (const float*)d_in[16];
    const float* l1_mu_b    = (const float*)d_in[17];
    const float* l2_um_W    = (const float*)d_in[18];
    const float* l2_um_asrc = (const float*)d_in[19];
    const float* l2_um_adst = (const float*)d_in[20];
    const float* l2_um_b    = (const float*)d_in[21];
    const float* l2_mu_W    = (const float*)d_in[22];
    const float* l2_mu_asrc = (const float*)d_in[23];
    const float* l2_mu_adst = (const float*)d_in[24];
    const float* l2_mu_b    = (const float*)d_in[25];
    const float* Wo         = (const float*)d_in[26];
    const float* bo         = (const float*)d_in[27];

    // ---- workspace carve (~68 MB) ----
    char* p = (char*)d_ws;
    auto alloc = [&](size_t bytes) { void* r = p; p += (bytes + 255) & ~(size_t)255; return r; };
    float* hs_u = (float*)alloc((size_t)Nu * HC * 4);
    float* hs_m = (float*)alloc((size_t)Nm * HC * 4);
    float* as_u = (float*)alloc((size_t)Nu * HH * 4);
    float* ad_u = (float*)alloc((size_t)Nu * HH * 4);
    float* as_m = (float*)alloc((size_t)Nm * HH * 4);
    float* ad_m = (float*)alloc((size_t)Nm * HH * 4);
    float* v_su = (float*)alloc(HC * HH * 4);
    float* v_du = (float*)alloc(HC * HH * 4);
    float* v_sm = (float*)alloc(HC * HH * 4);
    float* v_dm = (float*)alloc(HC * HH * 4);
    int* um_rs  = (int*)alloc((size_t)(Nm + 1) * 4);
    int* um_cnt = (int*)alloc((size_t)Nm * 4);
    int* um_csr = (int*)alloc((size_t)E1 * 4);
    int* mu_rs  = (int*)alloc((size_t)(Nu + 1) * 4);
    int* mu_cnt = (int*)alloc((size_t)Nu * 4);
    int* mu_csr = (int*)alloc((size_t)E2 * 4);
    int* partial = (int*)alloc(1024 * 4);

    auto cdiv = [](int a, int b) { return (a + b - 1) / b; };

    // ---- CSR build (per edge type, reused by both layers) ----
    auto build_csr = [&](const int* src, const int* dst, int E, int n,
                         int* rs, int* cnt, int* csr) {
        hipMemsetAsync(cnt, 0, (size_t)n * 4, stream);
        hist_k<<<cdiv(E, 256), 256, 0, stream>>>(dst, cnt, E);
        int len = n + 1, nb = cdiv(len, 256);
        scan_block_k<<<nb, 256, 0, stream>>>(cnt, n, len, rs, partial);
        scan_partial_k<<<1, 512, 0, stream>>>(partial, nb);
        add_off_k<<<nb, 256, 0, stream>>>(rs, partial, len);
        hipMemsetAsync(cnt, 0, (size_t)n * 4, stream);
        fill_k<<<cdiv(E, 256), 256, 0, stream>>>(src, dst, rs, cnt, csr, E);
    };
    build_csr(um_src, um_dst, E1, Nm, um_rs, um_cnt, um_csr);
    build_csr(mu_src, mu_dst, E2, Nu, mu_rs, mu_cnt, mu_csr);

    // output slots: [out_user | out_movie | xu | xm]
    float* OU = (float*)d_out;
    float* OM = OU + (size_t)Nu * O;
    float* XU = OM + (size_t)Nm * O;
    float* XM = XU + (size_t)Nu * HC;

    // ---- one hetero layer: both convs ----
    auto layer = [&](const float* xu, const int* uidx, const float* xm, const int* midx, int K,
                     const float* Wum_s, const float* Wum_d, const float* aum_s,
                     const float* aum_d, const float* b_um,
                     const float* Wmu_s, const float* Wmu_d, const float* amu_s,
                     const float* amu_d, const float* b_mu,
                     float* out_m, float* out_u) {
        int g4 = cdiv(K * HH, 256);
        make_v_k<<<g4, 256, 0, stream>>>(Wum_s, aum_s, v_su, K);
        make_v_k<<<g4, 256, 0, stream>>>(Wum_d, aum_d, v_du, K);
        make_v_k<<<g4, 256, 0, stream>>>(Wmu_s, amu_s, v_sm, K);
        make_v_k<<<g4, 256, 0, stream>>>(Wmu_d, amu_d, v_dm, K);
        gemm_f32<HC><<<cdiv(Nu, 128), 256, 0, stream>>>(xu, uidx, Wum_s, nullptr, hs_u, Nu, K);
        gemm_f32<HC><<<cdiv(Nm, 128), 256, 0, stream>>>(xm, midx, Wmu_s, nullptr, hs_m, Nm, K);
        node_att_k<<<cdiv(Nu, 4), 256, 0, stream>>>(xu, uidx, v_su, as_u, Nu, K);
        node_att_k<<<cdiv(Nm, 4), 256, 0, stream>>>(xm, midx, v_du, ad_m, Nm, K);
        node_att_k<<<cdiv(Nm, 4), 256, 0, stream>>>(xm, midx, v_sm, as_m, Nm, K);
        node_att_k<<<cdiv(Nu, 4), 256, 0, stream>>>(xu, uidx, v_dm, ad_u, Nu, K);
        agg_k<<<Nm, 256, 0, stream>>>(um_rs, um_csr, as_u, ad_m, hs_u, b_um, out_m, Nm);
        agg_k<<<Nu, 256, 0, stream>>>(mu_rs, mu_csr, as_m, ad_u, hs_m, b_mu, out_u, Nu);
    };

    // layer 1: src feats = raw embeddings (gathered via ids), K = D = 64
    layer(user_emb, user_ids, movie_emb, movie_ids, D,
          l1_um_Wsrc, l1_um_Wdst, l1_um_asrc, l1_um_adst, l1_um_b,
          l1_mu_Wsrc, l1_mu_Wdst, l1_mu_asrc, l1_mu_adst, l1_mu_b,
          XM, XU);
    // layer 2: feats = XU/XM (written in place after all reads), K = HC = 128
    layer(XU, nullptr, XM, nullptr, HC,
          l2_um_W, l2_um_W, l2_um_asrc, l2_um_adst, l2_um_b,
          l2_mu_W, l2_mu_W, l2_mu_asrc, l2_mu_adst, l2_mu_b,
          XM, XU);

    // final projection: out = x @ Wo + bo
    gemm_f32<64><<<cdiv(Nu, 128), 256, 0, stream>>>(XU, nullptr, Wo, bo, OU, Nu, HC);
    gemm_f32<64><<<cdiv(Nm, 128), 256, 0, stream>>>(XM, nullptr, Wo, bo, OM, Nm, HC);
}

// Round 2
// 640.464 us; speedup vs baseline: 1.0933x; 1.0933x over previous
//
#include <hip/hip_runtime.h>
#include <hip/hip_bf16.h>
#include <cstdint>

// ---------------------------------------------------------------------------
// HGAT: 2-layer hetero GAT (user<->movie), H=4 heads, C=32, HC=128, fp32.
// Per conv: hs = x_src @ Wsrc (GEMM). Attention logits fold to x @ v where
// v[k,h] = sum_c W[k,h*32+c]*a[h,c]; both src- and dst-side dots for each node
// type are packed into one V[K,8] -> att[n,8] pass.
// Edge pass (CSR by dst, 32 lanes per node, serial over edges):
//   out[d] = (sum_e exp(lrelu02(as[src]+ad[d])) * hs[src]) / (sum_e w) + b, lrelu01
// Softmax max-subtraction skipped (logits bounded; shift-invariant; validated).
// ---------------------------------------------------------------------------

#define HC 128   // H*C
#define HH 4     // heads

// ---------------- v[k, coff+h] = sum_c W[k,h*32+c]*a[h,c], v is [K,8] -------
__global__ void make_v_k(const float* __restrict__ W, const float* __restrict__ a,
                         float* __restrict__ v, int K, int coff) {
    int gid = blockIdx.x * 256 + threadIdx.x;
    if (gid >= K * HH) return;
    int k = gid >> 2, h = gid & 3;
    const float* wr = W + (size_t)k * HC + h * 32;
    const float* ar = a + h * 32;
    float s = 0.f;
    #pragma unroll
    for (int c = 0; c < 32; ++c) s = fmaf(wr[c], ar[c], s);
    v[k * 8 + coff + h] = s;
}

// ---------------- att[n,8] = x[row] @ V[K,8] (one wave per row) -------------
__global__ __launch_bounds__(256) void node_att8_k(
    const float* __restrict__ x, const int* __restrict__ idx,
    const float* __restrict__ v, float* __restrict__ att, int n, int K) {
    int wave = (int)((blockIdx.x * 256u + threadIdx.x) >> 6);
    int lane = threadIdx.x & 63;
    if (wave >= n) return;                       // uniform per wave
    int row = idx ? idx[wave] : wave;
    const float* xr = x + (size_t)row * K;
    float4 aL = make_float4(0.f, 0.f, 0.f, 0.f);
    float4 aH = make_float4(0.f, 0.f, 0.f, 0.f);
    for (int k = lane; k < K; k += 64) {
        float xv = xr[k];
        float4 vL = reinterpret_cast<const float4*>(v)[k * 2];
        float4 vH = reinterpret_cast<const float4*>(v)[k * 2 + 1];
        aL.x = fmaf(xv, vL.x, aL.x);
        aL.y = fmaf(xv, vL.y, aL.y);
        aL.z = fmaf(xv, vL.z, aL.z);
        aL.w = fmaf(xv, vL.w, aL.w);
        aH.x = fmaf(xv, vH.x, aH.x);
        aH.y = fmaf(xv, vH.y, aH.y);
        aH.z = fmaf(xv, vH.z, aH.z);
        aH.w = fmaf(xv, vH.w, aH.w);
    }
    #pragma unroll
    for (int off = 32; off; off >>= 1) {
        aL.x += __shfl_down(aL.x, off);
        aL.y += __shfl_down(aL.y, off);
        aL.z += __shfl_down(aL.z, off);
        aL.w += __shfl_down(aL.w, off);
        aH.x += __shfl_down(aH.x, off);
        aH.y += __shfl_down(aH.y, off);
        aH.z += __shfl_down(aH.z, off);
        aH.w += __shfl_down(aH.w, off);
    }
    if (lane == 0) {
        reinterpret_cast<float4*>(att)[wave * 2] = aL;
        reinterpret_cast<float4*>(att)[wave * 2 + 1] = aH;
    }
}

// ---------------- fp32 tiled GEMM: C[M,BN] = gather(A)[M,K] @ B[K,BN] (+bias)
template <int BN>
__global__ __launch_bounds__(256) void gemm_f32(
    const float* __restrict__ A, const int* __restrict__ aidx,
    const float* __restrict__ B, const float* __restrict__ bias,
    float* __restrict__ C, int M, int K) {
    constexpr int BM = 128, BK = 32;
    constexpr int TN = BN / 16;                  // 8 (BN=128) or 4 (BN=64)
    __shared__ __align__(16) float As[BK][BM + 4];   // transposed A tile
    __shared__ __align__(16) float Bs[BK][BN + 4];
    int tid = threadIdx.x;
    int tx = tid & 15, ty = tid >> 4;
    int m0 = blockIdx.x * BM;
    int row0 = ty * 8;
    int col0 = tx * TN;

    float acc[8][TN] = {};
    for (int kc = 0; kc < K; kc += BK) {
        for (int v = tid; v < BM * BK / 4; v += 256) {
            int ar = v >> 3;                     // BK/4 = 8 vec4 per row
            int ac4 = v & 7;
            float4 a4 = make_float4(0.f, 0.f, 0.f, 0.f);
            int grow = m0 + ar;
            if (grow < M) {
                int arow = aidx ? aidx[grow] : grow;
                a4 = *reinterpret_cast<const float4*>(&A[(size_t)arow * K + kc + ac4 * 4]);
            }
            As[ac4 * 4 + 0][ar] = a4.x;
            As[ac4 * 4 + 1][ar] = a4.y;
            As[ac4 * 4 + 2][ar] = a4.z;
            As[ac4 * 4 + 3][ar] = a4.w;
        }
        for (int v = tid; v < BK * BN / 4; v += 256) {
            int br = v / (BN / 4);
            int bc4 = v % (BN / 4);
            *reinterpret_cast<float4*>(&Bs[br][bc4 * 4]) =
                *reinterpret_cast<const float4*>(&B[(size_t)(kc + br) * BN + bc4 * 4]);
        }
        __syncthreads();
        #pragma unroll 4
        for (int kk = 0; kk < BK; ++kk) {
            float a[8];
            *reinterpret_cast<float4*>(&a[0]) = *reinterpret_cast<const float4*>(&As[kk][row0]);
            *reinterpret_cast<float4*>(&a[4]) = *reinterpret_cast<const float4*>(&As[kk][row0 + 4]);
            float b[TN];
            #pragma unroll
            for (int j = 0; j < TN; j += 4)
                *reinterpret_cast<float4*>(&b[j]) = *reinterpret_cast<const float4*>(&Bs[kk][col0 + j]);
            #pragma unroll
            for (int i = 0; i < 8; ++i)
                #pragma unroll
                for (int j = 0; j < TN; ++j)
                    acc[i][j] = fmaf(a[i], b[j], acc[i][j]);
        }
        __syncthreads();
    }
    float bv[TN];
    #pragma unroll
    for (int j = 0; j < TN; ++j) bv[j] = bias ? bias[col0 + j] : 0.f;
    #pragma unroll
    for (int i = 0; i < 8; ++i) {
        int gr = m0 + row0 + i;
        if (gr < M) {
            #pragma unroll
            for (int j = 0; j < TN; j += 4) {
                float4 o = make_float4(acc[i][j] + bv[j], acc[i][j + 1] + bv[j + 1],
                                       acc[i][j + 2] + bv[j + 2], acc[i][j + 3] + bv[j + 3]);
                *reinterpret_cast<float4*>(&C[(size_t)gr * BN + col0 + j]) = o;
            }
        }
    }
}

// ---------------- CSR build ------------------------------------------------
__global__ void hist_k(const int* __restrict__ dst, int* __restrict__ deg, int E) {
    int e = blockIdx.x * 256 + threadIdx.x;
    if (e < E) atomicAdd(&deg[dst[e]], 1);
}

__global__ void scan_block_k(const int* __restrict__ deg, int n, int len,
                             int* __restrict__ out, int* __restrict__ partial) {
    __shared__ int s[256];
    int i = blockIdx.x * 256 + threadIdx.x;
    int v = (i < n) ? deg[i] : 0;
    s[threadIdx.x] = v;
    __syncthreads();
    for (int off = 1; off < 256; off <<= 1) {
        int t = (threadIdx.x >= off) ? s[threadIdx.x - off] : 0;
        __syncthreads();
        s[threadIdx.x] += t;
        __syncthreads();
    }
    if (i < len) out[i] = s[threadIdx.x] - v;    // exclusive within block
    if (threadIdx.x == 255) partial[blockIdx.x] = s[255];
}

__global__ void scan_partial_k(int* __restrict__ partial, int nb) {
    __shared__ int s[512];
    int t = threadIdx.x;
    int v = (t < nb) ? partial[t] : 0;
    s[t] = v;
    __syncthreads();
    for (int off = 1; off < 512; off <<= 1) {
        int x = (t >= off) ? s[t - off] : 0;
        __syncthreads();
        s[t] += x;
        __syncthreads();
    }
    if (t < nb) partial[t] = s[t] - v;           // exclusive
}

__global__ void add_off_k(int* __restrict__ out, const int* __restrict__ partial, int len) {
    int i = blockIdx.x * 256 + threadIdx.x;
    if (i < len) out[i] += partial[i >> 8];
}

__global__ void fill_k(const int* __restrict__ src, const int* __restrict__ dst,
                       const int* __restrict__ rs, int* __restrict__ cnt,
                       int* __restrict__ csr_src, int E) {
    int e = blockIdx.x * 256 + threadIdx.x;
    if (e < E) {
        int d = dst[e];
        int pos = rs[d] + atomicAdd(&cnt[d], 1);
        csr_src[pos] = src[e];
    }
}

// ---------------- per-dst aggregation: 32 lanes per node, serial edges ------
// att_s has stride 8 (cols 0-3 = src logits); att_d passed pre-offset (+4).
__global__ __launch_bounds__(256) void agg_k(
    const int* __restrict__ rs, const int* __restrict__ csr_src,
    const float* __restrict__ att_s, const float* __restrict__ att_d,
    const float* __restrict__ hs, const float* __restrict__ bias,
    float* __restrict__ out, int n) {
    int node = (int)((blockIdx.x * 256u + threadIdx.x) >> 5);   // 8 nodes/block
    if (node >= n) return;
    int c = threadIdx.x & 31;    // float4 group: channels 4c..4c+3
    int h = c >> 3;              // head
    float ad = att_d[node * 8 + h];
    int s0 = rs[node], s1 = rs[node + 1];
    float4 acc = make_float4(0.f, 0.f, 0.f, 0.f);
    float wsum = 0.f;
    int i = s0;
    for (; i + 2 <= s1; i += 2) {            // 2 gathers in flight
        int src0 = csr_src[i];
        int src1 = csr_src[i + 1];
        float4 h0 = reinterpret_cast<const float4*>(hs)[(size_t)src0 * 32 + c];
        float4 h1 = reinterpret_cast<const float4*>(hs)[(size_t)src1 * 32 + c];
        float e0 = att_s[src0 * 8 + h] + ad;
        float e1 = att_s[src1 * 8 + h] + ad;
        e0 = e0 > 0.f ? e0 : 0.2f * e0;
        e1 = e1 > 0.f ? e1 : 0.2f * e1;
        float w0 = __expf(e0);
        float w1 = __expf(e1);
        wsum += w0 + w1;
        acc.x = fmaf(w0, h0.x, fmaf(w1, h1.x, acc.x));
        acc.y = fmaf(w0, h0.y, fmaf(w1, h1.y, acc.y));
        acc.z = fmaf(w0, h0.z, fmaf(w1, h1.z, acc.z));
        acc.w = fmaf(w0, h0.w, fmaf(w1, h1.w, acc.w));
    }
    if (i < s1) {
        int src0 = csr_src[i];
        float4 h0 = reinterpret_cast<const float4*>(hs)[(size_t)src0 * 32 + c];
        float e0 = att_s[src0 * 8 + h] + ad;
        e0 = e0 > 0.f ? e0 : 0.2f * e0;
        float w0 = __expf(e0);
        wsum += w0;
        acc.x = fmaf(w0, h0.x, acc.x);
        acc.y = fmaf(w0, h0.y, acc.y);
        acc.z = fmaf(w0, h0.z, acc.z);
        acc.w = fmaf(w0, h0.w, acc.w);
    }
    float inv = 1.f / (wsum + 1e-16f);
    float4 b4 = reinterpret_cast<const float4*>(bias)[c];
    float4 v;
    v.x = fmaf(acc.x, inv, b4.x);
    v.y = fmaf(acc.y, inv, b4.y);
    v.z = fmaf(acc.z, inv, b4.z);
    v.w = fmaf(acc.w, inv, b4.w);
    v.x = v.x > 0.f ? v.x : 0.01f * v.x;
    v.y = v.y > 0.f ? v.y : 0.01f * v.y;
    v.z = v.z > 0.f ? v.z : 0.01f * v.z;
    v.w = v.w > 0.f ? v.w : 0.01f * v.w;
    reinterpret_cast<float4*>(out)[(size_t)node * 32 + c] = v;
}

// ---------------------------------------------------------------------------
extern "C" void kernel_launch(void* const* d_in, const int* in_sizes, int n_in,
                              void* d_out, int out_size, void* d_ws, size_t ws_size,
                              hipStream_t stream) {
    const int Nu = in_sizes[0];
    const int Nm = in_sizes[1];
    const int E1 = in_sizes[2];   // um edges
    const int E2 = in_sizes[4];   // mu edges
    const int D  = in_sizes[6] / Nu;   // 64
    const int O  = in_sizes[27];       // 64

    const int*   user_ids  = (const int*)d_in[0];
    const int*   movie_ids = (const int*)d_in[1];
    const int*   um_src    = (const int*)d_in[2];
    const int*   um_dst    = (const int*)d_in[3];
    const int*   mu_src    = (const int*)d_in[4];
    const int*   mu_dst    = (const int*)d_in[5];
    const float* user_emb  = (const float*)d_in[6];
    const float* movie_emb = (const float*)d_in[7];
    const float* l1_um_Wsrc = (const float*)d_in[8];
    const float* l1_um_Wdst = (const float*)d_in[9];
    const float* l1_um_asrc = (const float*)d_in[10];
    const float* l1_um_adst = (const float*)d_in[11];
    const float* l1_um_b    = (const float*)d_in[12];
    const float* l1_mu_Wsrc = (const float*)d_in[13];
    const float* l1_mu_Wdst = (const float*)d_in[14];
    const float* l1_mu_asrc = (const float*)d_in[15];
    const float* l1_mu_adst = (const float*)d_in[16];
    const float* l1_mu_b    = (const float*)d_in[17];
    const float* l2_um_W    = (const float*)d_in[18];
    const float* l2_um_asrc = (const float*)d_in[19];
    const float* l2_um_adst = (const float*)d_in[20];
    const float* l2_um_b    = (const float*)d_in[21];
    const float* l2_mu_W    = (const float*)d_in[22];
    const float* l2_mu_asrc = (const float*)d_in[23];
    const float* l2_mu_adst = (const float*)d_in[24];
    const float* l2_mu_b    = (const float*)d_in[25];
    const float* Wo         = (const float*)d_in[26];
    const float* bo         = (const float*)d_in[27];

    // ---- workspace carve ----
    char* p = (char*)d_ws;
    auto alloc = [&](size_t bytes) { void* r = p; p += (bytes + 255) & ~(size_t)255; return r; };
    float* hs_u  = (float*)alloc((size_t)Nu * HC * 4);
    float* hs_m  = (float*)alloc((size_t)Nm * HC * 4);
    float* att_u = (float*)alloc((size_t)Nu * 8 * 4);   // cols 0-3 src, 4-7 dst
    float* att_m = (float*)alloc((size_t)Nm * 8 * 4);
    float* V_u   = (float*)alloc((size_t)HC * 8 * 4);
    float* V_m   = (float*)alloc((size_t)HC * 8 * 4);
    int* um_rs  = (int*)alloc((size_t)(Nm + 1) * 4);
    int* um_cnt = (int*)alloc((size_t)Nm * 4);
    int* um_csr = (int*)alloc((size_t)E1 * 4);
    int* mu_rs  = (int*)alloc((size_t)(Nu + 1) * 4);
    int* mu_cnt = (int*)alloc((size_t)Nu * 4);
    int* mu_csr = (int*)alloc((size_t)E2 * 4);
    int* partial = (int*)alloc(1024 * 4);

    auto cdiv = [](int a, int b) { return (a + b - 1) / b; };

    // ---- CSR build (per edge type, reused by both layers) ----
    auto build_csr = [&](const int* src, const int* dst, int E, int n,
                         int* rs, int* cnt, int* csr) {
        hipMemsetAsync(cnt, 0, (size_t)n * 4, stream);
        hist_k<<<cdiv(E, 256), 256, 0, stream>>>(dst, cnt, E);
        int len = n + 1, nb = cdiv(len, 256);
        scan_block_k<<<nb, 256, 0, stream>>>(cnt, n, len, rs, partial);
        scan_partial_k<<<1, 512, 0, stream>>>(partial, nb);
        add_off_k<<<nb, 256, 0, stream>>>(rs, partial, len);
        hipMemsetAsync(cnt, 0, (size_t)n * 4, stream);
        fill_k<<<cdiv(E, 256), 256, 0, stream>>>(src, dst, rs, cnt, csr, E);
    };
    build_csr(um_src, um_dst, E1, Nm, um_rs, um_cnt, um_csr);
    build_csr(mu_src, mu_dst, E2, Nu, mu_rs, mu_cnt, mu_csr);

    // output slots: [out_user | out_movie | xu | xm]
    float* OU = (float*)d_out;
    float* OM = OU + (size_t)Nu * O;
    float* XU = OM + (size_t)Nm * O;
    float* XM = XU + (size_t)Nu * HC;

    // ---- one hetero layer: both convs ----
    auto layer = [&](const float* xu, const int* uidx, const float* xm, const int* midx, int K,
                     const float* Wum_s, const float* Wum_d, const float* aum_s,
                     const float* aum_d, const float* b_um,
                     const float* Wmu_s, const float* Wmu_d, const float* amu_s,
                     const float* amu_d, const float* b_mu,
                     float* out_m, float* out_u) {
        int g4 = cdiv(K * HH, 256);
        make_v_k<<<g4, 256, 0, stream>>>(Wum_s, aum_s, V_u, K, 0);  // user as um-src
        make_v_k<<<g4, 256, 0, stream>>>(Wmu_d, amu_d, V_u, K, 4);  // user as mu-dst
        make_v_k<<<g4, 256, 0, stream>>>(Wmu_s, amu_s, V_m, K, 0);  // movie as mu-src
        make_v_k<<<g4, 256, 0, stream>>>(Wum_d, aum_d, V_m, K, 4);  // movie as um-dst
        gemm_f32<HC><<<cdiv(Nu, 128), 256, 0, stream>>>(xu, uidx, Wum_s, nullptr, hs_u, Nu, K);
        gemm_f32<HC><<<cdiv(Nm, 128), 256, 0, stream>>>(xm, midx, Wmu_s, nullptr, hs_m, Nm, K);
        node_att8_k<<<cdiv(Nu, 4), 256, 0, stream>>>(xu, uidx, V_u, att_u, Nu, K);
        node_att8_k<<<cdiv(Nm, 4), 256, 0, stream>>>(xm, midx, V_m, att_m, Nm, K);
        agg_k<<<cdiv(Nm, 8), 256, 0, stream>>>(um_rs, um_csr, att_u, att_m + 4, hs_u, b_um, out_m, Nm);
        agg_k<<<cdiv(Nu, 8), 256, 0, stream>>>(mu_rs, mu_csr, att_m, att_u + 4, hs_m, b_mu, out_u, Nu);
    };

    // layer 1: src feats = raw embeddings (gathered via ids), K = D = 64
    layer(user_emb, user_ids, movie_emb, movie_ids, D,
          l1_um_Wsrc, l1_um_Wdst, l1_um_asrc, l1_um_adst, l1_um_b,
          l1_mu_Wsrc, l1_mu_Wdst, l1_mu_asrc, l1_mu_adst, l1_mu_b,
          XM, XU);
    // layer 2: feats = XU/XM (written in place after all reads), K = HC = 128
    layer(XU, nullptr, XM, nullptr, HC,
          l2_um_W, l2_um_W, l2_um_asrc, l2_um_adst, l2_um_b,
          l2_mu_W, l2_mu_W, l2_mu_asrc, l2_mu_adst, l2_mu_b,
          XM, XU);

    // final projection: out = x @ Wo + bo
    gemm_f32<64><<<cdiv(Nu, 128), 256, 0, stream>>>(XU, nullptr, Wo, bo, OU, Nu, HC);
    gemm_f32<64><<<cdiv(Nm, 128), 256, 0, stream>>>(XM, nullptr, Wo, bo, OM, Nm, HC);
}

// Round 3
// 435.528 us; speedup vs baseline: 1.6078x; 1.4705x over previous
//
#include <hip/hip_runtime.h>
#include <hip/hip_bf16.h>
#include <cstdint>

// ---------------------------------------------------------------------------
// HGAT: 2-layer hetero GAT (user<->movie), H=4 heads, C=32, HC=128.
// GEMMs run on bf16 MFMA (16x16x32), fp32 accumulate; inputs converted to
// bf16 in-register (A) / once-per-layer pack kernel (W). The folded attention
// matrix V[K,8] is appended to the packed weights so hs and att come out of
// ONE GEMM pass (no separate node_att kernel).
// Edge pass (CSR by dst, 32 lanes per node, serial over edges):
//   out[d] = (sum_e exp(lrelu02(as[src]+ad[d])) * hs[src]) / (sum_e w) + b, lrelu01
// Softmax max-subtraction skipped (logits bounded; shift-invariant; validated).
// ---------------------------------------------------------------------------

#define HC 128   // H*C
#define HH 4     // heads

typedef __attribute__((ext_vector_type(8))) short bf16x8;   // 8 bf16 (4 VGPR)
typedef __attribute__((ext_vector_type(4))) float f32x4;    // MFMA acc

__device__ __forceinline__ short f2bf(float f) {
    return __builtin_bit_cast(short, __float2bfloat16(f));
}

// ---------------- v[k, coff+h] = sum_c W[k,h*32+c]*a[h,c], v is [K,8] -------
__global__ void make_v_k(const float* __restrict__ W, const float* __restrict__ a,
                         float* __restrict__ v, int K, int coff) {
    int gid = blockIdx.x * 256 + threadIdx.x;
    if (gid >= K * HH) return;
    int k = gid >> 2, h = gid & 3;
    const float* wr = W + (size_t)k * HC + h * 32;
    const float* ar = a + h * 32;
    float s = 0.f;
    #pragma unroll
    for (int c = 0; c < 32; ++c) s = fmaf(wr[c], ar[c], s);
    v[k * 8 + coff + h] = s;
}

// ---------------- pack Wb[n][k] = bf16(W[k][n]) ; rows Nw..Nw+7 = V[k][n-Nw] -
__global__ void pack_w_k(const float* __restrict__ W, const float* __restrict__ V,
                         ushort* __restrict__ Wb, int K, int Nw, int Nrows) {
    int gid = blockIdx.x * 256 + threadIdx.x;
    if (gid >= Nrows * K) return;
    int n = gid / K, k = gid % K;
    float v = 0.f;
    if (n < Nw) v = W[(size_t)k * Nw + n];
    else if (V != nullptr && n < Nw + 8) v = V[k * 8 + (n - Nw)];
    Wb[gid] = (ushort)f2bf(v);
}

// ---------------- bf16 MFMA GEMM: C[M,NW] = gather(A)[M,K] @ Wb^T  ----------
// Wb is [NT*16][K] bf16 (row n = column n of W). If ATT, last tile's cols 0-7
// are the folded attention logits -> written to att[M,8]. No LDS, no barriers.
template <int NT, bool ATT, bool BIAS>
__global__ __launch_bounds__(256) void gemm_mfma_k(
    const float* __restrict__ A, const int* __restrict__ aidx,
    const ushort* __restrict__ Wb, const float* __restrict__ bias,
    float* __restrict__ C, int ldc, float* __restrict__ att, int M, int K) {
    int lane = threadIdx.x & 63;
    int wave = threadIdx.x >> 6;
    int m_base = blockIdx.x * 128 + wave * 32;
    int lm = lane & 15;      // A row-in-tile / C col-in-tile
    int kg = lane >> 4;      // k-group (8 consecutive k per group)

    int r0 = m_base + lm, r1 = r0 + 16;
    int cr0 = r0 < M ? r0 : M - 1;
    int cr1 = r1 < M ? r1 : M - 1;
    int row0 = aidx ? aidx[cr0] : cr0;
    int row1 = aidx ? aidx[cr1] : cr1;
    const float* a0p = A + (size_t)row0 * K + kg * 8;
    const float* a1p = A + (size_t)row1 * K + kg * 8;
    const ushort* bp = Wb + (size_t)lm * K + kg * 8;

    f32x4 acc[2][NT] = {};
    for (int k0 = 0; k0 < K; k0 += 32) {
        float af[2][8];
        *reinterpret_cast<float4*>(&af[0][0]) = *reinterpret_cast<const float4*>(a0p + k0);
        *reinterpret_cast<float4*>(&af[0][4]) = *reinterpret_cast<const float4*>(a0p + k0 + 4);
        *reinterpret_cast<float4*>(&af[1][0]) = *reinterpret_cast<const float4*>(a1p + k0);
        *reinterpret_cast<float4*>(&af[1][4]) = *reinterpret_cast<const float4*>(a1p + k0 + 4);
        bf16x8 a[2];
        #pragma unroll
        for (int mi = 0; mi < 2; ++mi)
            #pragma unroll
            for (int j = 0; j < 8; ++j) a[mi][j] = f2bf(af[mi][j]);
        #pragma unroll
        for (int nt = 0; nt < NT; ++nt) {
            bf16x8 b = *reinterpret_cast<const bf16x8*>(bp + (size_t)nt * 16 * K + k0);
            acc[0][nt] = __builtin_amdgcn_mfma_f32_16x16x32_bf16(a[0], b, acc[0][nt], 0, 0, 0);
            acc[1][nt] = __builtin_amdgcn_mfma_f32_16x16x32_bf16(a[1], b, acc[1][nt], 0, 0, 0);
        }
    }
    constexpr int NW = ATT ? NT - 1 : NT;   // C tiles (last tile = att if ATT)
    #pragma unroll
    for (int mi = 0; mi < 2; ++mi) {
        int rowb = m_base + mi * 16 + kg * 4;
        #pragma unroll
        for (int nt = 0; nt < NW; ++nt) {
            int col = nt * 16 + lm;
            float bv = BIAS ? bias[col] : 0.f;
            #pragma unroll
            for (int r = 0; r < 4; ++r) {
                int row = rowb + r;
                if (row < M) C[(size_t)row * ldc + col] = acc[mi][nt][r] + bv;
            }
        }
        if (ATT && lm < 8) {
            #pragma unroll
            for (int r = 0; r < 4; ++r) {
                int row = rowb + r;
                if (row < M) att[(size_t)row * 8 + lm] = acc[mi][NT - 1][r];
            }
        }
    }
}

// ---------------- CSR build ------------------------------------------------
__global__ void hist_k(const int* __restrict__ dst, int* __restrict__ deg, int E) {
    int e = blockIdx.x * 256 + threadIdx.x;
    if (e < E) atomicAdd(&deg[dst[e]], 1);
}

__global__ void scan_block_k(const int* __restrict__ deg, int n, int len,
                             int* __restrict__ out, int* __restrict__ partial) {
    __shared__ int s[256];
    int i = blockIdx.x * 256 + threadIdx.x;
    int v = (i < n) ? deg[i] : 0;
    s[threadIdx.x] = v;
    __syncthreads();
    for (int off = 1; off < 256; off <<= 1) {
        int t = (threadIdx.x >= off) ? s[threadIdx.x - off] : 0;
        __syncthreads();
        s[threadIdx.x] += t;
        __syncthreads();
    }
    if (i < len) out[i] = s[threadIdx.x] - v;    // exclusive within block
    if (threadIdx.x == 255) partial[blockIdx.x] = s[255];
}

__global__ void scan_partial_k(int* __restrict__ partial, int nb) {
    __shared__ int s[512];
    int t = threadIdx.x;
    int v = (t < nb) ? partial[t] : 0;
    s[t] = v;
    __syncthreads();
    for (int off = 1; off < 512; off <<= 1) {
        int x = (t >= off) ? s[t - off] : 0;
        __syncthreads();
        s[t] += x;
        __syncthreads();
    }
    if (t < nb) partial[t] = s[t] - v;           // exclusive
}

__global__ void add_off_k(int* __restrict__ out, const int* __restrict__ partial, int len) {
    int i = blockIdx.x * 256 + threadIdx.x;
    if (i < len) out[i] += partial[i >> 8];
}

__global__ void fill_k(const int* __restrict__ src, const int* __restrict__ dst,
                       const int* __restrict__ rs, int* __restrict__ cnt,
                       int* __restrict__ csr_src, int E) {
    int e = blockIdx.x * 256 + threadIdx.x;
    if (e < E) {
        int d = dst[e];
        int pos = rs[d] + atomicAdd(&cnt[d], 1);
        csr_src[pos] = src[e];
    }
}

// ---------------- per-dst aggregation: 32 lanes per node, serial edges ------
// att_s has stride 8 (cols 0-3 = src logits); att_d passed pre-offset (+4).
__global__ __launch_bounds__(256) void agg_k(
    const int* __restrict__ rs, const int* __restrict__ csr_src,
    const float* __restrict__ att_s, const float* __restrict__ att_d,
    const float* __restrict__ hs, const float* __restrict__ bias,
    float* __restrict__ out, int n) {
    int node = (int)((blockIdx.x * 256u + threadIdx.x) >> 5);   // 8 nodes/block
    if (node >= n) return;
    int c = threadIdx.x & 31;    // float4 group: channels 4c..4c+3
    int h = c >> 3;              // head
    float ad = att_d[node * 8 + h];
    int s0 = rs[node], s1 = rs[node + 1];
    float4 acc = make_float4(0.f, 0.f, 0.f, 0.f);
    float wsum = 0.f;
    int i = s0;
    for (; i + 2 <= s1; i += 2) {            // 2 gathers in flight
        int src0 = csr_src[i];
        int src1 = csr_src[i + 1];
        float4 h0 = reinterpret_cast<const float4*>(hs)[(size_t)src0 * 32 + c];
        float4 h1 = reinterpret_cast<const float4*>(hs)[(size_t)src1 * 32 + c];
        float e0 = att_s[src0 * 8 + h] + ad;
        float e1 = att_s[src1 * 8 + h] + ad;
        e0 = e0 > 0.f ? e0 : 0.2f * e0;
        e1 = e1 > 0.f ? e1 : 0.2f * e1;
        float w0 = __expf(e0);
        float w1 = __expf(e1);
        wsum += w0 + w1;
        acc.x = fmaf(w0, h0.x, fmaf(w1, h1.x, acc.x));
        acc.y = fmaf(w0, h0.y, fmaf(w1, h1.y, acc.y));
        acc.z = fmaf(w0, h0.z, fmaf(w1, h1.z, acc.z));
        acc.w = fmaf(w0, h0.w, fmaf(w1, h1.w, acc.w));
    }
    if (i < s1) {
        int src0 = csr_src[i];
        float4 h0 = reinterpret_cast<const float4*>(hs)[(size_t)src0 * 32 + c];
        float e0 = att_s[src0 * 8 + h] + ad;
        e0 = e0 > 0.f ? e0 : 0.2f * e0;
        float w0 = __expf(e0);
        wsum += w0;
        acc.x = fmaf(w0, h0.x, acc.x);
        acc.y = fmaf(w0, h0.y, acc.y);
        acc.z = fmaf(w0, h0.z, acc.z);
        acc.w = fmaf(w0, h0.w, acc.w);
    }
    float inv = 1.f / (wsum + 1e-16f);
    float4 b4 = reinterpret_cast<const float4*>(bias)[c];
    float4 v;
    v.x = fmaf(acc.x, inv, b4.x);
    v.y = fmaf(acc.y, inv, b4.y);
    v.z = fmaf(acc.z, inv, b4.z);
    v.w = fmaf(acc.w, inv, b4.w);
    v.x = v.x > 0.f ? v.x : 0.01f * v.x;
    v.y = v.y > 0.f ? v.y : 0.01f * v.y;
    v.z = v.z > 0.f ? v.z : 0.01f * v.z;
    v.w = v.w > 0.f ? v.w : 0.01f * v.w;
    reinterpret_cast<float4*>(out)[(size_t)node * 32 + c] = v;
}

// ---------------------------------------------------------------------------
extern "C" void kernel_launch(void* const* d_in, const int* in_sizes, int n_in,
                              void* d_out, int out_size, void* d_ws, size_t ws_size,
                              hipStream_t stream) {
    const int Nu = in_sizes[0];
    const int Nm = in_sizes[1];
    const int E1 = in_sizes[2];   // um edges
    const int E2 = in_sizes[4];   // mu edges
    const int D  = in_sizes[6] / Nu;   // 64
    const int O  = in_sizes[27];       // 64

    const int*   user_ids  = (const int*)d_in[0];
    const int*   movie_ids = (const int*)d_in[1];
    const int*   um_src    = (const int*)d_in[2];
    const int*   um_dst    = (const int*)d_in[3];
    const int*   mu_src    = (const int*)d_in[4];
    const int*   mu_dst    = (const int*)d_in[5];
    const float* user_emb  = (const float*)d_in[6];
    const float* movie_emb = (const float*)d_in[7];
    const float* l1_um_Wsrc = (const float*)d_in[8];
    const float* l1_um_Wdst = (const float*)d_in[9];
    const float* l1_um_asrc = (const float*)d_in[10];
    const float* l1_um_adst = (const float*)d_in[11];
    const float* l1_um_b    = (const float*)d_in[12];
    const float* l1_mu_Wsrc = (const float*)d_in[13];
    const float* l1_mu_Wdst = (const float*)d_in[14];
    const float* l1_mu_asrc = (const float*)d_in[15];
    const float* l1_mu_adst = (const float*)d_in[16];
    const float* l1_mu_b    = (const float*)d_in[17];
    const float* l2_um_W    = (const float*)d_in[18];
    const float* l2_um_asrc = (const float*)d_in[19];
    const float* l2_um_adst = (const float*)d_in[20];
    const float* l2_um_b    = (const float*)d_in[21];
    const float* l2_mu_W    = (const float*)d_in[22];
    const float* l2_mu_asrc = (const float*)d_in[23];
    const float* l2_mu_adst = (const float*)d_in[24];
    const float* l2_mu_b    = (const float*)d_in[25];
    const float* Wo         = (const float*)d_in[26];
    const float* bo         = (const float*)d_in[27];

    // ---- workspace carve ----
    char* p = (char*)d_ws;
    auto alloc = [&](size_t bytes) { void* r = p; p += (bytes + 255) & ~(size_t)255; return r; };
    float* hs_u  = (float*)alloc((size_t)Nu * HC * 4);
    float* hs_m  = (float*)alloc((size_t)Nm * HC * 4);
    float* att_u = (float*)alloc((size_t)Nu * 8 * 4);   // cols 0-3 src, 4-7 dst
    float* att_m = (float*)alloc((size_t)Nm * 8 * 4);
    float* V_u1  = (float*)alloc((size_t)HC * 8 * 4);
    float* V_m1  = (float*)alloc((size_t)HC * 8 * 4);
    float* V_u2  = (float*)alloc((size_t)HC * 8 * 4);
    float* V_m2  = (float*)alloc((size_t)HC * 8 * 4);
    ushort* Wb_u1 = (ushort*)alloc((size_t)144 * D * 2);
    ushort* Wb_m1 = (ushort*)alloc((size_t)144 * D * 2);
    ushort* Wb_u2 = (ushort*)alloc((size_t)144 * HC * 2);
    ushort* Wb_m2 = (ushort*)alloc((size_t)144 * HC * 2);
    ushort* Wb_o  = (ushort*)alloc((size_t)64 * HC * 2);
    int* um_rs  = (int*)alloc((size_t)(Nm + 1) * 4);
    int* um_cnt = (int*)alloc((size_t)Nm * 4);
    int* um_csr = (int*)alloc((size_t)E1 * 4);
    int* mu_rs  = (int*)alloc((size_t)(Nu + 1) * 4);
    int* mu_cnt = (int*)alloc((size_t)Nu * 4);
    int* mu_csr = (int*)alloc((size_t)E2 * 4);
    int* partial = (int*)alloc(1024 * 4);

    auto cdiv = [](int a, int b) { return (a + b - 1) / b; };

    // ---- fold attention vectors, pack weights (all x-independent) ----
    {
        int g1 = cdiv(D * HH, 256), g2 = cdiv(HC * HH, 256);
        make_v_k<<<g1, 256, 0, stream>>>(l1_um_Wsrc, l1_um_asrc, V_u1, D, 0);
        make_v_k<<<g1, 256, 0, stream>>>(l1_mu_Wdst, l1_mu_adst, V_u1, D, 4);
        make_v_k<<<g1, 256, 0, stream>>>(l1_mu_Wsrc, l1_mu_asrc, V_m1, D, 0);
        make_v_k<<<g1, 256, 0, stream>>>(l1_um_Wdst, l1_um_adst, V_m1, D, 4);
        make_v_k<<<g2, 256, 0, stream>>>(l2_um_W, l2_um_asrc, V_u2, HC, 0);
        make_v_k<<<g2, 256, 0, stream>>>(l2_mu_W, l2_mu_adst, V_u2, HC, 4);
        make_v_k<<<g2, 256, 0, stream>>>(l2_mu_W, l2_mu_asrc, V_m2, HC, 0);
        make_v_k<<<g2, 256, 0, stream>>>(l2_um_W, l2_um_adst, V_m2, HC, 4);
        pack_w_k<<<cdiv(144 * D, 256), 256, 0, stream>>>(l1_um_Wsrc, V_u1, Wb_u1, D, HC, 144);
        pack_w_k<<<cdiv(144 * D, 256), 256, 0, stream>>>(l1_mu_Wsrc, V_m1, Wb_m1, D, HC, 144);
        pack_w_k<<<cdiv(144 * HC, 256), 256, 0, stream>>>(l2_um_W, V_u2, Wb_u2, HC, HC, 144);
        pack_w_k<<<cdiv(144 * HC, 256), 256, 0, stream>>>(l2_mu_W, V_m2, Wb_m2, HC, HC, 144);
        pack_w_k<<<cdiv(64 * HC, 256), 256, 0, stream>>>(Wo, nullptr, Wb_o, HC, 64, 64);
    }

    // ---- CSR build (per edge type, reused by both layers) ----
    auto build_csr = [&](const int* src, const int* dst, int E, int n,
                         int* rs, int* cnt, int* csr) {
        hipMemsetAsync(cnt, 0, (size_t)n * 4, stream);
        hist_k<<<cdiv(E, 256), 256, 0, stream>>>(dst, cnt, E);
        int len = n + 1, nb = cdiv(len, 256);
        scan_block_k<<<nb, 256, 0, stream>>>(cnt, n, len, rs, partial);
        scan_partial_k<<<1, 512, 0, stream>>>(partial, nb);
        add_off_k<<<nb, 256, 0, stream>>>(rs, partial, len);
        hipMemsetAsync(cnt, 0, (size_t)n * 4, stream);
        fill_k<<<cdiv(E, 256), 256, 0, stream>>>(src, dst, rs, cnt, csr, E);
    };
    build_csr(um_src, um_dst, E1, Nm, um_rs, um_cnt, um_csr);
    build_csr(mu_src, mu_dst, E2, Nu, mu_rs, mu_cnt, mu_csr);

    // output slots: [out_user | out_movie | xu | xm]
    float* OU = (float*)d_out;
    float* OM = OU + (size_t)Nu * O;
    float* XU = OM + (size_t)Nm * O;
    float* XM = XU + (size_t)Nu * HC;

    // ---- one hetero layer: both convs (hs+att in one MFMA GEMM each) ----
    auto layer = [&](const float* xu, const int* uidx, const float* xm, const int* midx, int K,
                     const ushort* Wbu, const ushort* Wbm,
                     const float* b_um, const float* b_mu,
                     float* out_m, float* out_u) {
        gemm_mfma_k<9, true, false><<<cdiv(Nu, 128), 256, 0, stream>>>(
            xu, uidx, Wbu, nullptr, hs_u, HC, att_u, Nu, K);
        gemm_mfma_k<9, true, false><<<cdiv(Nm, 128), 256, 0, stream>>>(
            xm, midx, Wbm, nullptr, hs_m, HC, att_m, Nm, K);
        agg_k<<<cdiv(Nm, 8), 256, 0, stream>>>(um_rs, um_csr, att_u, att_m + 4, hs_u, b_um, out_m, Nm);
        agg_k<<<cdiv(Nu, 8), 256, 0, stream>>>(mu_rs, mu_csr, att_m, att_u + 4, hs_m, b_mu, out_u, Nu);
    };

    // layer 1: src feats = raw embeddings (gathered via ids), K = D = 64
    layer(user_emb, user_ids, movie_emb, movie_ids, D,
          Wb_u1, Wb_m1, l1_um_b, l1_mu_b, XM, XU);
    // layer 2: feats = XU/XM (written in place after all reads), K = HC = 128
    layer(XU, nullptr, XM, nullptr, HC,
          Wb_u2, Wb_m2, l2_um_b, l2_mu_b, XM, XU);

    // final projection: out = x @ Wo + bo  (no activation)
    gemm_mfma_k<4, false, true><<<cdiv(Nu, 128), 256, 0, stream>>>(
        XU, nullptr, Wb_o, bo, OU, O, nullptr, Nu, HC);
    gemm_mfma_k<4, false, true><<<cdiv(Nm, 128), 256, 0, stream>>>(
        XM, nullptr, Wb_o, bo, OM, O, nullptr, Nm, HC);
}

// Round 4
// 308.662 us; speedup vs baseline: 2.2687x; 1.4110x over previous
//
#include <hip/hip_runtime.h>
#include <hip/hip_bf16.h>
#include <cstdint>

// ---------------------------------------------------------------------------
// HGAT: 2-layer hetero GAT (user<->movie), H=4 heads, C=32, HC=128.
// GEMMs on bf16 MFMA 16x16x32, fp32 accumulate. hs stored bf16 with the 4
// folded src attention logits packed into the row tail (stride 136 ushorts =
// 272B = exactly 5 cache lines) so the per-edge gather touches 5 lines instead
// of 9. Activations kept in fp32 (d_out, reference output) AND bf16 (ws) so
// layer-2/proj GEMM A-loads are direct bf16x8. Dual-segment kernels (user+
// movie in one launch) cut the dispatch count to 14.
// Edge pass (CSR by dst, 32 lanes/node): out[d] = (sum_e w_e*hs[src]) /
// (sum_e w_e) + b with w = exp(lrelu02(as[src]+ad[d])); lrelu01 after.
// Softmax max-subtraction skipped (logits bounded; shift-invariant; validated).
// ---------------------------------------------------------------------------

#define HC 128
#define HH 4
#define HSTRIDE 136   // 128 bf16 channels + 4 bf16 src logits + 4 pad

typedef __attribute__((ext_vector_type(8))) short bf16x8;
typedef __attribute__((ext_vector_type(4))) float f32x4;

__device__ __forceinline__ short f2bf(float f) {
    return __builtin_bit_cast(short, __float2bfloat16(f));
}
__device__ __forceinline__ float bf2f(ushort u) {
    return __builtin_bit_cast(float, ((unsigned)u) << 16);
}

// ---------------- fold attention: v[k, coff+h] = sum_c W[k,h*32+c]*a[h,c] ---
// 8 tasks in one launch. Tasks 0-3: K=64 (256 elems each); 4-7: K=128 (512).
struct VT { const float* W[8]; const float* a[8]; float* v[8]; };
__global__ void make_v_all_k(VT t) {
    int gid = blockIdx.x * 256 + threadIdx.x;
    int task, base, K;
    if (gid < 1024) { task = gid >> 8; base = gid & 255; K = 64; }
    else if (gid < 3072) { int g = gid - 1024; task = 4 + (g >> 9); base = g & 511; K = 128; }
    else return;
    int k = base >> 2, h = base & 3;
    int coff = (task & 1) * 4;
    const float* wr = t.W[task] + (size_t)k * HC + h * 32;
    const float* ar = t.a[task] + h * 32;
    float s = 0.f;
    #pragma unroll
    for (int c = 0; c < 32; ++c) s = fmaf(wr[c], ar[c], s);
    t.v[task][k * 8 + coff + h] = s;
}

// ---------------- pack Wb[n][k] = bf16(W[k][n]); rows Nw..Nw+7 = V ----------
struct PT { const float* W[5]; const float* V[5]; ushort* Wb[5];
            int K[5]; int Nw[5]; int start[6]; };
__global__ void pack_all_k(PT t) {
    int gid = blockIdx.x * 256 + threadIdx.x;
    if (gid >= t.start[5]) return;
    int task = 0;
    while (gid >= t.start[task + 1]) ++task;
    int loc = gid - t.start[task];
    int K = t.K[task], Nw = t.Nw[task];
    int n = loc / K, k = loc % K;
    float v = 0.f;
    if (n < Nw) v = t.W[task][(size_t)k * Nw + n];
    else if (t.V[task] != nullptr && n < Nw + 8) v = t.V[task][k * 8 + (n - Nw)];
    t.Wb[task][loc] = (ushort)f2bf(v);
}

// ---------------- dual-segment bf16 MFMA GEMM -------------------------------
// MODE 0: hs out (bf16, HSTRIDE) + att-dst fp32 [M,4] + att-src bf16 row tail.
// MODE 1: fp32 C[M,ldc] + bias. ABF: A is dense bf16 (ushort), else fp32+idx.
template <int NT, int MODE, bool ABF>
__global__ __launch_bounds__(256) void gemm_dual_k(
    const void* A0, const int* idx0, const ushort* Wb0, ushort* hsb0,
    float* att0, float* C0, int M0, int nb0,
    const void* A1, const int* idx1, const ushort* Wb1, ushort* hsb1,
    float* att1, float* C1, int M1,
    const float* bias, int K, int ldc) {
    const void* A; const int* aidx; const ushort* Wb; ushort* hsb;
    float* att; float* C; int M, bid;
    if ((int)blockIdx.x < nb0) {
        A = A0; aidx = idx0; Wb = Wb0; hsb = hsb0; att = att0; C = C0; M = M0;
        bid = blockIdx.x;
    } else {
        A = A1; aidx = idx1; Wb = Wb1; hsb = hsb1; att = att1; C = C1; M = M1;
        bid = blockIdx.x - nb0;
    }
    int lane = threadIdx.x & 63;
    int wave = threadIdx.x >> 6;
    int m_base = bid * 128 + wave * 32;
    int lm = lane & 15;      // A row-in-tile / C col-in-tile
    int kg = lane >> 4;      // k-group (8 consecutive k)

    int r0 = m_base + lm, r1 = r0 + 16;
    int cr0 = r0 < M ? r0 : M - 1;
    int cr1 = r1 < M ? r1 : M - 1;
    int row0 = aidx ? aidx[cr0] : cr0;
    int row1 = aidx ? aidx[cr1] : cr1;
    const ushort* bp = Wb + (size_t)lm * K + kg * 8;

    f32x4 acc[2][NT] = {};
    for (int k0 = 0; k0 < K; k0 += 32) {
        bf16x8 a[2];
        if (ABF) {
            const ushort* a0p = (const ushort*)A + (size_t)row0 * K + kg * 8;
            const ushort* a1p = (const ushort*)A + (size_t)row1 * K + kg * 8;
            a[0] = *reinterpret_cast<const bf16x8*>(a0p + k0);
            a[1] = *reinterpret_cast<const bf16x8*>(a1p + k0);
        } else {
            const float* a0p = (const float*)A + (size_t)row0 * K + kg * 8;
            const float* a1p = (const float*)A + (size_t)row1 * K + kg * 8;
            float af[2][8];
            *reinterpret_cast<float4*>(&af[0][0]) = *reinterpret_cast<const float4*>(a0p + k0);
            *reinterpret_cast<float4*>(&af[0][4]) = *reinterpret_cast<const float4*>(a0p + k0 + 4);
            *reinterpret_cast<float4*>(&af[1][0]) = *reinterpret_cast<const float4*>(a1p + k0);
            *reinterpret_cast<float4*>(&af[1][4]) = *reinterpret_cast<const float4*>(a1p + k0 + 4);
            #pragma unroll
            for (int mi = 0; mi < 2; ++mi)
                #pragma unroll
                for (int j = 0; j < 8; ++j) a[mi][j] = f2bf(af[mi][j]);
        }
        #pragma unroll
        for (int nt = 0; nt < NT; ++nt) {
            bf16x8 b = *reinterpret_cast<const bf16x8*>(bp + (size_t)nt * 16 * K + k0);
            acc[0][nt] = __builtin_amdgcn_mfma_f32_16x16x32_bf16(a[0], b, acc[0][nt], 0, 0, 0);
            acc[1][nt] = __builtin_amdgcn_mfma_f32_16x16x32_bf16(a[1], b, acc[1][nt], 0, 0, 0);
        }
    }
    #pragma unroll
    for (int mi = 0; mi < 2; ++mi) {
        int rowb = m_base + mi * 16 + kg * 4;
        if (MODE == 0) {
            #pragma unroll
            for (int nt = 0; nt < NT - 1; ++nt) {
                int col = nt * 16 + lm;
                #pragma unroll
                for (int r = 0; r < 4; ++r) {
                    int row = rowb + r;
                    if (row < M) hsb[(size_t)row * HSTRIDE + col] = (ushort)f2bf(acc[mi][nt][r]);
                }
            }
            // last tile: cols 0-3 = src logits -> row tail; 4-7 = dst -> att
            #pragma unroll
            for (int r = 0; r < 4; ++r) {
                int row = rowb + r;
                if (row < M) {
                    float v = acc[mi][NT - 1][r];
                    if (lm < 4) hsb[(size_t)row * HSTRIDE + 128 + lm] = (ushort)f2bf(v);
                    else if (lm < 8) att[(size_t)row * 4 + (lm - 4)] = v;
                }
            }
        } else {
            #pragma unroll
            for (int nt = 0; nt < NT; ++nt) {
                int col = nt * 16 + lm;
                float bv = bias[col];
                #pragma unroll
                for (int r = 0; r < 4; ++r) {
                    int row = rowb + r;
                    if (row < M) C[(size_t)row * ldc + col] = acc[mi][nt][r] + bv;
                }
            }
        }
    }
}

// ---------------- CSR build (dual edge-type) --------------------------------
__global__ void hist_dual_k(const int* __restrict__ d0, int* __restrict__ c0, int E0,
                            const int* __restrict__ d1, int* __restrict__ c1, int E1) {
    int e = blockIdx.x * 256 + threadIdx.x;
    if (e < E0) atomicAdd(&c0[d0[e]], 1);
    else if (e - E0 < E1) atomicAdd(&c1[d1[e - E0]], 1);
}

__device__ __forceinline__ void scan_block_body(
    const int* deg, int n, int len, int* out, int* partial, int b) {
    __shared__ int s[256];
    int i = b * 256 + threadIdx.x;
    int v = (i < n) ? deg[i] : 0;
    s[threadIdx.x] = v;
    __syncthreads();
    for (int off = 1; off < 256; off <<= 1) {
        int t = (threadIdx.x >= off) ? s[threadIdx.x - off] : 0;
        __syncthreads();
        s[threadIdx.x] += t;
        __syncthreads();
    }
    if (i < len) out[i] = s[threadIdx.x] - v;
    if (threadIdx.x == 255) partial[b] = s[255];
}

__global__ void scan_block_dual_k(const int* dM, int nM, int* rsM, int* pM, int nbM,
                                  const int* dU, int nU, int* rsU, int* pU) {
    if ((int)blockIdx.x < nbM)
        scan_block_body(dM, nM, nM + 1, rsM, pM, blockIdx.x);
    else
        scan_block_body(dU, nU, nU + 1, rsU, pU, blockIdx.x - nbM);
}

__global__ void scan_partial_dual_k(int* pM, int nbM, int* pU, int nbU) {
    __shared__ int s[512];
    int t = threadIdx.x;
    for (int seg = 0; seg < 2; ++seg) {
        int* p = seg ? pU : pM;
        int nb = seg ? nbU : nbM;
        int v = (t < nb) ? p[t] : 0;
        s[t] = v;
        __syncthreads();
        for (int off = 1; off < 512; off <<= 1) {
            int x = (t >= off) ? s[t - off] : 0;
            __syncthreads();
            s[t] += x;
            __syncthreads();
        }
        if (t < nb) p[t] = s[t] - v;
        __syncthreads();
    }
}

__global__ void add_off_dual_k(int* __restrict__ oM, const int* __restrict__ pM,
                               int lenM, int nbM,
                               int* __restrict__ oU, const int* __restrict__ pU,
                               int lenU) {
    int b = blockIdx.x;
    if (b < nbM) {
        int i = b * 256 + threadIdx.x;
        if (i < lenM) oM[i] += pM[b];
    } else {
        b -= nbM;
        int i = b * 256 + threadIdx.x;
        if (i < lenU) oU[i] += pU[b];
    }
}

__global__ void fill_dual_k(const int* s0, const int* d0, const int* rs0,
                            int* c0, int* csr0, int E0,
                            const int* s1, const int* d1, const int* rs1,
                            int* c1, int* csr1, int E1) {
    int e = blockIdx.x * 256 + threadIdx.x;
    if (e < E0) {
        int d = d0[e];
        csr0[rs0[d] + atomicAdd(&c0[d], 1)] = s0[e];
    } else if (e - E0 < E1) {
        e -= E0;
        int d = d1[e];
        csr1[rs1[d] + atomicAdd(&c1[d], 1)] = s1[e];
    }
}

// ---------------- dual per-dst aggregation: 32 lanes/node, serial edges -----
__global__ __launch_bounds__(256) void agg_dual_k(
    const int* rs0, const int* csr0, const ushort* hsb0, const float* attd0,
    const float* bias0, float* out0, ushort* outb0, int n0,
    const int* rs1, const int* csr1, const ushort* hsb1, const float* attd1,
    const float* bias1, float* out1, ushort* outb1, int n1) {
    int g = (int)((blockIdx.x * 256u + threadIdx.x) >> 5);
    const int* rs; const int* csr; const ushort* hsb; const float* attd;
    const float* bias; float* out; ushort* outb; int node;
    if (g < n0) {
        rs = rs0; csr = csr0; hsb = hsb0; attd = attd0; bias = bias0;
        out = out0; outb = outb0; node = g;
    } else {
        node = g - n0;
        if (node >= n1) return;
        rs = rs1; csr = csr1; hsb = hsb1; attd = attd1; bias = bias1;
        out = out1; outb = outb1;
    }
    int c = threadIdx.x & 31;    // channel group 4c..4c+3
    int h = c >> 3;              // head
    float ad = attd[node * 4 + h];
    int s0 = rs[node], s1 = rs[node + 1];
    float4 acc = make_float4(0.f, 0.f, 0.f, 0.f);
    float wsum = 0.f;
    int i = s0;
    for (; i + 4 <= s1; i += 4) {
        int sx[4];
        #pragma unroll
        for (int j = 0; j < 4; ++j) sx[j] = csr[i + j];
        ushort4 hv[4]; float el[4];
        #pragma unroll
        for (int j = 0; j < 4; ++j) {
            const ushort* rp = hsb + (size_t)sx[j] * HSTRIDE;
            hv[j] = *reinterpret_cast<const ushort4*>(rp + 4 * c);
            el[j] = bf2f(rp[128 + h]);
        }
        #pragma unroll
        for (int j = 0; j < 4; ++j) {
            float e = el[j] + ad;
            e = e > 0.f ? e : 0.2f * e;
            float w = __expf(e);
            wsum += w;
            acc.x = fmaf(w, bf2f(hv[j].x), acc.x);
            acc.y = fmaf(w, bf2f(hv[j].y), acc.y);
            acc.z = fmaf(w, bf2f(hv[j].z), acc.z);
            acc.w = fmaf(w, bf2f(hv[j].w), acc.w);
        }
    }
    for (; i < s1; ++i) {
        int src = csr[i];
        const ushort* rp = hsb + (size_t)src * HSTRIDE;
        ushort4 hv = *reinterpret_cast<const ushort4*>(rp + 4 * c);
        float e = bf2f(rp[128 + h]) + ad;
        e = e > 0.f ? e : 0.2f * e;
        float w = __expf(e);
        wsum += w;
        acc.x = fmaf(w, bf2f(hv.x), acc.x);
        acc.y = fmaf(w, bf2f(hv.y), acc.y);
        acc.z = fmaf(w, bf2f(hv.z), acc.z);
        acc.w = fmaf(w, bf2f(hv.w), acc.w);
    }
    float inv = 1.f / (wsum + 1e-16f);
    float4 b4 = reinterpret_cast<const float4*>(bias)[c];
    float4 v;
    v.x = fmaf(acc.x, inv, b4.x);
    v.y = fmaf(acc.y, inv, b4.y);
    v.z = fmaf(acc.z, inv, b4.z);
    v.w = fmaf(acc.w, inv, b4.w);
    v.x = v.x > 0.f ? v.x : 0.01f * v.x;
    v.y = v.y > 0.f ? v.y : 0.01f * v.y;
    v.z = v.z > 0.f ? v.z : 0.01f * v.z;
    v.w = v.w > 0.f ? v.w : 0.01f * v.w;
    reinterpret_cast<float4*>(out + (size_t)node * HC)[c] = v;
    ushort4 vb;
    vb.x = (ushort)f2bf(v.x); vb.y = (ushort)f2bf(v.y);
    vb.z = (ushort)f2bf(v.z); vb.w = (ushort)f2bf(v.w);
    reinterpret_cast<ushort4*>(outb + (size_t)node * HC)[c] = vb;
}

// ---------------------------------------------------------------------------
extern "C" void kernel_launch(void* const* d_in, const int* in_sizes, int n_in,
                              void* d_out, int out_size, void* d_ws, size_t ws_size,
                              hipStream_t stream) {
    const int Nu = in_sizes[0];
    const int Nm = in_sizes[1];
    const int E1 = in_sizes[2];   // um edges
    const int E2 = in_sizes[4];   // mu edges
    const int D  = in_sizes[6] / Nu;   // 64
    const int O  = in_sizes[27];       // 64

    const int*   user_ids  = (const int*)d_in[0];
    const int*   movie_ids = (const int*)d_in[1];
    const int*   um_src    = (const int*)d_in[2];
    const int*   um_dst    = (const int*)d_in[3];
    const int*   mu_src    = (const int*)d_in[4];
    const int*   mu_dst    = (const int*)d_in[5];
    const float* user_emb  = (const float*)d_in[6];
    const float* movie_emb = (const float*)d_in[7];
    const float* l1_um_Wsrc = (const float*)d_in[8];
    const float* l1_um_Wdst = (const float*)d_in[9];
    const float* l1_um_asrc = (const float*)d_in[10];
    const float* l1_um_adst = (const float*)d_in[11];
    const float* l1_um_b    = (const float*)d_in[12];
    const float* l1_mu_Wsrc = (const float*)d_in[13];
    const float* l1_mu_Wdst = (const float*)d_in[14];
    const float* l1_mu_asrc = (const float*)d_in[15];
    const float* l1_mu_adst = (const float*)d_in[16];
    const float* l1_mu_b    = (const float*)d_in[17];
    const float* l2_um_W    = (const float*)d_in[18];
    const float* l2_um_asrc = (const float*)d_in[19];
    const float* l2_um_adst = (const float*)d_in[20];
    const float* l2_um_b    = (const float*)d_in[21];
    const float* l2_mu_W    = (const float*)d_in[22];
    const float* l2_mu_asrc = (const float*)d_in[23];
    const float* l2_mu_adst = (const float*)d_in[24];
    const float* l2_mu_b    = (const float*)d_in[25];
    const float* Wo         = (const float*)d_in[26];
    const float* bo         = (const float*)d_in[27];

    // ---- workspace carve ----
    char* p = (char*)d_ws;
    auto alloc = [&](size_t bytes) { void* r = p; p += (bytes + 255) & ~(size_t)255; return r; };
    ushort* hs_u = (ushort*)alloc((size_t)Nu * HSTRIDE * 2);
    ushort* hs_m = (ushort*)alloc((size_t)Nm * HSTRIDE * 2);
    ushort* XUb  = (ushort*)alloc((size_t)Nu * HC * 2);
    ushort* XMb  = (ushort*)alloc((size_t)Nm * HC * 2);
    float* att_u = (float*)alloc((size_t)Nu * 4 * 4);   // dst logits only
    float* att_m = (float*)alloc((size_t)Nm * 4 * 4);
    float* V_u1  = (float*)alloc((size_t)HC * 8 * 4);
    float* V_m1  = (float*)alloc((size_t)HC * 8 * 4);
    float* V_u2  = (float*)alloc((size_t)HC * 8 * 4);
    float* V_m2  = (float*)alloc((size_t)HC * 8 * 4);
    ushort* Wb_u1 = (ushort*)alloc((size_t)144 * D * 2);
    ushort* Wb_m1 = (ushort*)alloc((size_t)144 * D * 2);
    ushort* Wb_u2 = (ushort*)alloc((size_t)144 * HC * 2);
    ushort* Wb_m2 = (ushort*)alloc((size_t)144 * HC * 2);
    ushort* Wb_o  = (ushort*)alloc((size_t)64 * HC * 2);
    int* um_rs  = (int*)alloc((size_t)(Nm + 1) * 4);
    int* mu_rs  = (int*)alloc((size_t)(Nu + 1) * 4);
    int* cnts   = (int*)alloc((size_t)(Nm + Nu) * 4);   // um_cnt | mu_cnt
    int* um_cnt = cnts;
    int* mu_cnt = cnts + Nm;
    int* um_csr = (int*)alloc((size_t)E1 * 4);
    int* mu_csr = (int*)alloc((size_t)E2 * 4);
    int* partM  = (int*)alloc(512 * 4);
    int* partU  = (int*)alloc(512 * 4);

    auto cdiv = [](int a, int b) { return (a + b - 1) / b; };

    // ---- fold attention + pack weights (x-independent) ----
    {
        VT vt;
        const float* Ws[8] = {l1_um_Wsrc, l1_mu_Wdst, l1_mu_Wsrc, l1_um_Wdst,
                              l2_um_W, l2_mu_W, l2_mu_W, l2_um_W};
        const float* as[8] = {l1_um_asrc, l1_mu_adst, l1_mu_asrc, l1_um_adst,
                              l2_um_asrc, l2_mu_adst, l2_mu_asrc, l2_um_adst};
        float* vs[8] = {V_u1, V_u1, V_m1, V_m1, V_u2, V_u2, V_m2, V_m2};
        for (int i = 0; i < 8; ++i) { vt.W[i] = Ws[i]; vt.a[i] = as[i]; vt.v[i] = vs[i]; }
        make_v_all_k<<<12, 256, 0, stream>>>(vt);

        PT pt;
        const float* pW[5] = {l1_um_Wsrc, l1_mu_Wsrc, l2_um_W, l2_mu_W, Wo};
        const float* pV[5] = {V_u1, V_m1, V_u2, V_m2, nullptr};
        ushort* pB[5] = {Wb_u1, Wb_m1, Wb_u2, Wb_m2, Wb_o};
        int pK[5] = {D, D, HC, HC, HC};
        int pN[5] = {HC, HC, HC, HC, 64};
        int cum = 0;
        for (int i = 0; i < 5; ++i) {
            pt.W[i] = pW[i]; pt.V[i] = pV[i]; pt.Wb[i] = pB[i];
            pt.K[i] = pK[i]; pt.Nw[i] = pN[i];
            pt.start[i] = cum;
            cum += (i < 4 ? 144 : 64) * pK[i];
        }
        pt.start[5] = cum;
        pack_all_k<<<cdiv(cum, 256), 256, 0, stream>>>(pt);
    }

    // ---- CSR build (both edge types, reused by both layers) ----
    int nbM = cdiv(Nm + 1, 256), nbU = cdiv(Nu + 1, 256);
    hipMemsetAsync(cnts, 0, (size_t)(Nm + Nu) * 4, stream);
    hist_dual_k<<<cdiv(E1 + E2, 256), 256, 0, stream>>>(um_dst, um_cnt, E1, mu_dst, mu_cnt, E2);
    scan_block_dual_k<<<nbM + nbU, 256, 0, stream>>>(um_cnt, Nm, um_rs, partM, nbM,
                                                     mu_cnt, Nu, mu_rs, partU);
    scan_partial_dual_k<<<1, 512, 0, stream>>>(partM, nbM, partU, nbU);
    add_off_dual_k<<<nbM + nbU, 256, 0, stream>>>(um_rs, partM, Nm + 1, nbM,
                                                  mu_rs, partU, Nu + 1);
    hipMemsetAsync(cnts, 0, (size_t)(Nm + Nu) * 4, stream);
    fill_dual_k<<<cdiv(E1 + E2, 256), 256, 0, stream>>>(
        um_src, um_dst, um_rs, um_cnt, um_csr, E1,
        mu_src, mu_dst, mu_rs, mu_cnt, mu_csr, E2);

    // output slots: [out_user | out_movie | xu | xm]
    float* OU = (float*)d_out;
    float* OM = OU + (size_t)Nu * O;
    float* XU = OM + (size_t)Nm * O;
    float* XM = XU + (size_t)Nu * HC;

    int gbU = cdiv(Nu, 128), gbM = cdiv(Nm, 128);
    int aggBlocks = cdiv((Nm + Nu) * 32, 256);

    // ---- layer 1: A = fp32 embeddings (gathered), K = D ----
    gemm_dual_k<9, 0, false><<<gbU + gbM, 256, 0, stream>>>(
        user_emb, user_ids, Wb_u1, hs_u, att_u, nullptr, Nu, gbU,
        movie_emb, movie_ids, Wb_m1, hs_m, att_m, nullptr, Nm,
        nullptr, D, 0);
    agg_dual_k<<<aggBlocks, 256, 0, stream>>>(
        um_rs, um_csr, hs_u, att_m, l1_um_b, XM, XMb, Nm,
        mu_rs, mu_csr, hs_m, att_u, l1_mu_b, XU, XUb, Nu);

    // ---- layer 2: A = bf16 activations, K = HC ----
    gemm_dual_k<9, 0, true><<<gbU + gbM, 256, 0, stream>>>(
        XUb, nullptr, Wb_u2, hs_u, att_u, nullptr, Nu, gbU,
        XMb, nullptr, Wb_m2, hs_m, att_m, nullptr, Nm,
        nullptr, HC, 0);
    agg_dual_k<<<aggBlocks, 256, 0, stream>>>(
        um_rs, um_csr, hs_u, att_m, l2_um_b, XM, XMb, Nm,
        mu_rs, mu_csr, hs_m, att_u, l2_mu_b, XU, XUb, Nu);

    // ---- final projection: out = x @ Wo + bo ----
    gemm_dual_k<4, 1, true><<<gbU + gbM, 256, 0, stream>>>(
        XUb, nullptr, Wb_o, nullptr, nullptr, OU, Nu, gbU,
        XMb, nullptr, Wb_o, nullptr, nullptr, OM, Nm,
        bo, HC, O);
}

// Round 5
// 296.394 us; speedup vs baseline: 2.3626x; 1.0414x over previous
//
#include <hip/hip_runtime.h>
#include <hip/hip_bf16.h>
#include <cstdint>

// ---------------------------------------------------------------------------
// HGAT: 2-layer hetero GAT (user<->movie), H=4 heads, C=32, HC=128.
// GEMMs on bf16 MFMA 16x16x32, fp32 accumulate. hs stored bf16 as ALIGNED
// 256B rows (4 cache lines/edge gather). Folded attention logits go to small
// separate fp32 [N,4] arrays (L2-resident, gather is mostly L2-hit).
// Layer-1 agg writes ONLY bf16 activations (fp32 slot would be overwritten);
// layer-2 agg writes ONLY fp32 (proj GEMM reads fp32 directly).
// Edge pass (CSR by dst, 32 lanes/node): out[d] = (sum_e w_e*hs[src]) /
// (sum_e w_e) + b with w = exp(lrelu02(as[src]+ad[d])); lrelu01 after.
// Softmax max-subtraction skipped (logits bounded; shift-invariant; validated).
// ---------------------------------------------------------------------------

#define HC 128
#define HH 4

typedef __attribute__((ext_vector_type(8))) short bf16x8;
typedef __attribute__((ext_vector_type(4))) float f32x4;

__device__ __forceinline__ short f2bf(float f) {
    return __builtin_bit_cast(short, __float2bfloat16(f));
}
__device__ __forceinline__ float bf2f(ushort u) {
    return __builtin_bit_cast(float, ((unsigned)u) << 16);
}

// ---------------- fold attention: v[k, coff+h] = sum_c W[k,h*32+c]*a[h,c] ---
// 8 tasks in one launch. Tasks 0-3: K=64 (256 elems each); 4-7: K=128 (512).
struct VT { const float* W[8]; const float* a[8]; float* v[8]; };
__global__ void make_v_all_k(VT t) {
    int gid = blockIdx.x * 256 + threadIdx.x;
    int task, base;
    if (gid < 1024) { task = gid >> 8; base = gid & 255; }
    else if (gid < 3072) { int g = gid - 1024; task = 4 + (g >> 9); base = g & 511; }
    else return;
    int k = base >> 2, h = base & 3;
    int coff = (task & 1) * 4;
    const float* wr = t.W[task] + (size_t)k * HC + h * 32;
    const float* ar = t.a[task] + h * 32;
    float s = 0.f;
    #pragma unroll
    for (int c = 0; c < 32; ++c) s = fmaf(wr[c], ar[c], s);
    t.v[task][k * 8 + coff + h] = s;
}

// ---------------- pack Wb[n][k] = bf16(W[k][n]); rows Nw..Nw+7 = V ----------
struct PT { const float* W[5]; const float* V[5]; ushort* Wb[5];
            int K[5]; int Nw[5]; int start[6]; };
__global__ void pack_all_k(PT t) {
    int gid = blockIdx.x * 256 + threadIdx.x;
    if (gid >= t.start[5]) return;
    int task = 0;
    while (gid >= t.start[task + 1]) ++task;
    int loc = gid - t.start[task];
    int K = t.K[task], Nw = t.Nw[task];
    int n = loc / K, k = loc % K;
    float v = 0.f;
    if (n < Nw) v = t.W[task][(size_t)k * Nw + n];
    else if (t.V[task] != nullptr && n < Nw + 8) v = t.V[task][k * 8 + (n - Nw)];
    t.Wb[task][loc] = (ushort)f2bf(v);
}

// ---------------- dual-segment bf16 MFMA GEMM -------------------------------
// MODE 0: hs out (bf16 [M,128]) + atts fp32 [M,4] + attd fp32 [M,4].
// MODE 1: fp32 C[M,ldc] + bias. ABF: A is dense bf16 (ushort), else fp32+idx.
template <int NT, int MODE, bool ABF>
__global__ __launch_bounds__(256) void gemm_dual_k(
    const void* A0, const int* idx0, const ushort* Wb0, ushort* hsb0,
    float* atts0, float* attd0, float* C0, int M0, int nb0,
    const void* A1, const int* idx1, const ushort* Wb1, ushort* hsb1,
    float* atts1, float* attd1, float* C1, int M1,
    const float* bias, int K, int ldc) {
    const void* A; const int* aidx; const ushort* Wb; ushort* hsb;
    float* atts; float* attd; float* C; int M, bid;
    if ((int)blockIdx.x < nb0) {
        A = A0; aidx = idx0; Wb = Wb0; hsb = hsb0; atts = atts0; attd = attd0;
        C = C0; M = M0; bid = blockIdx.x;
    } else {
        A = A1; aidx = idx1; Wb = Wb1; hsb = hsb1; atts = atts1; attd = attd1;
        C = C1; M = M1; bid = blockIdx.x - nb0;
    }
    int lane = threadIdx.x & 63;
    int wave = threadIdx.x >> 6;
    int m_base = bid * 128 + wave * 32;
    int lm = lane & 15;      // A row-in-tile / C col-in-tile
    int kg = lane >> 4;      // k-group (8 consecutive k)

    int r0 = m_base + lm, r1 = r0 + 16;
    int cr0 = r0 < M ? r0 : M - 1;
    int cr1 = r1 < M ? r1 : M - 1;
    int row0 = aidx ? aidx[cr0] : cr0;
    int row1 = aidx ? aidx[cr1] : cr1;
    const ushort* bp = Wb + (size_t)lm * K + kg * 8;

    f32x4 acc[2][NT] = {};
    for (int k0 = 0; k0 < K; k0 += 32) {
        bf16x8 a[2];
        if (ABF) {
            const ushort* a0p = (const ushort*)A + (size_t)row0 * K + kg * 8;
            const ushort* a1p = (const ushort*)A + (size_t)row1 * K + kg * 8;
            a[0] = *reinterpret_cast<const bf16x8*>(a0p + k0);
            a[1] = *reinterpret_cast<const bf16x8*>(a1p + k0);
        } else {
            const float* a0p = (const float*)A + (size_t)row0 * K + kg * 8;
            const float* a1p = (const float*)A + (size_t)row1 * K + kg * 8;
            float af[2][8];
            *reinterpret_cast<float4*>(&af[0][0]) = *reinterpret_cast<const float4*>(a0p + k0);
            *reinterpret_cast<float4*>(&af[0][4]) = *reinterpret_cast<const float4*>(a0p + k0 + 4);
            *reinterpret_cast<float4*>(&af[1][0]) = *reinterpret_cast<const float4*>(a1p + k0);
            *reinterpret_cast<float4*>(&af[1][4]) = *reinterpret_cast<const float4*>(a1p + k0 + 4);
            #pragma unroll
            for (int mi = 0; mi < 2; ++mi)
                #pragma unroll
                for (int j = 0; j < 8; ++j) a[mi][j] = f2bf(af[mi][j]);
        }
        #pragma unroll
        for (int nt = 0; nt < NT; ++nt) {
            bf16x8 b = *reinterpret_cast<const bf16x8*>(bp + (size_t)nt * 16 * K + k0);
            acc[0][nt] = __builtin_amdgcn_mfma_f32_16x16x32_bf16(a[0], b, acc[0][nt], 0, 0, 0);
            acc[1][nt] = __builtin_amdgcn_mfma_f32_16x16x32_bf16(a[1], b, acc[1][nt], 0, 0, 0);
        }
    }
    #pragma unroll
    for (int mi = 0; mi < 2; ++mi) {
        int rowb = m_base + mi * 16 + kg * 4;
        if (MODE == 0) {
            #pragma unroll
            for (int nt = 0; nt < NT - 1; ++nt) {
                int col = nt * 16 + lm;
                #pragma unroll
                for (int r = 0; r < 4; ++r) {
                    int row = rowb + r;
                    if (row < M) hsb[(size_t)row * HC + col] = (ushort)f2bf(acc[mi][nt][r]);
                }
            }
            // last tile: cols 0-3 = src logits, 4-7 = dst logits (fp32 arrays)
            #pragma unroll
            for (int r = 0; r < 4; ++r) {
                int row = rowb + r;
                if (row < M) {
                    float v = acc[mi][NT - 1][r];
                    if (lm < 4) atts[(size_t)row * 4 + lm] = v;
                    else if (lm < 8) attd[(size_t)row * 4 + (lm - 4)] = v;
                }
            }
        } else {
            #pragma unroll
            for (int nt = 0; nt < NT; ++nt) {
                int col = nt * 16 + lm;
                float bv = bias[col];
                #pragma unroll
                for (int r = 0; r < 4; ++r) {
                    int row = rowb + r;
                    if (row < M) C[(size_t)row * ldc + col] = acc[mi][nt][r] + bv;
                }
            }
        }
    }
}

// ---------------- CSR build (dual edge-type) --------------------------------
__global__ void hist_dual_k(const int* __restrict__ d0, int* __restrict__ c0, int E0,
                            const int* __restrict__ d1, int* __restrict__ c1, int E1) {
    int e = blockIdx.x * 256 + threadIdx.x;
    if (e < E0) atomicAdd(&c0[d0[e]], 1);
    else if (e - E0 < E1) atomicAdd(&c1[d1[e - E0]], 1);
}

__device__ __forceinline__ void scan_block_body(
    const int* deg, int n, int len, int* out, int* partial, int b) {
    __shared__ int s[256];
    int i = b * 256 + threadIdx.x;
    int v = (i < n) ? deg[i] : 0;
    s[threadIdx.x] = v;
    __syncthreads();
    for (int off = 1; off < 256; off <<= 1) {
        int t = (threadIdx.x >= off) ? s[threadIdx.x - off] : 0;
        __syncthreads();
        s[threadIdx.x] += t;
        __syncthreads();
    }
    if (i < len) out[i] = s[threadIdx.x] - v;
    if (threadIdx.x == 255) partial[b] = s[255];
}

__global__ void scan_block_dual_k(const int* dM, int nM, int* rsM, int* pM, int nbM,
                                  const int* dU, int nU, int* rsU, int* pU) {
    if ((int)blockIdx.x < nbM)
        scan_block_body(dM, nM, nM + 1, rsM, pM, blockIdx.x);
    else
        scan_block_body(dU, nU, nU + 1, rsU, pU, blockIdx.x - nbM);
}

__global__ void scan_partial_dual_k(int* pM, int nbM, int* pU, int nbU) {
    __shared__ int s[512];
    int t = threadIdx.x;
    for (int seg = 0; seg < 2; ++seg) {
        int* p = seg ? pU : pM;
        int nb = seg ? nbU : nbM;
        int v = (t < nb) ? p[t] : 0;
        s[t] = v;
        __syncthreads();
        for (int off = 1; off < 512; off <<= 1) {
            int x = (t >= off) ? s[t - off] : 0;
            __syncthreads();
            s[t] += x;
            __syncthreads();
        }
        if (t < nb) p[t] = s[t] - v;
        __syncthreads();
    }
}

__global__ void add_off_dual_k(int* __restrict__ oM, const int* __restrict__ pM,
                               int lenM, int nbM,
                               int* __restrict__ oU, const int* __restrict__ pU,
                               int lenU) {
    int b = blockIdx.x;
    if (b < nbM) {
        int i = b * 256 + threadIdx.x;
        if (i < lenM) oM[i] += pM[b];
    } else {
        b -= nbM;
        int i = b * 256 + threadIdx.x;
        if (i < lenU) oU[i] += pU[b];
    }
}

__global__ void fill_dual_k(const int* s0, const int* d0, const int* rs0,
                            int* c0, int* csr0, int E0,
                            const int* s1, const int* d1, const int* rs1,
                            int* c1, int* csr1, int E1) {
    int e = blockIdx.x * 256 + threadIdx.x;
    if (e < E0) {
        int d = d0[e];
        csr0[rs0[d] + atomicAdd(&c0[d], 1)] = s0[e];
    } else if (e - E0 < E1) {
        e -= E0;
        int d = d1[e];
        csr1[rs1[d] + atomicAdd(&c1[d], 1)] = s1[e];
    }
}

// ---------------- dual per-dst aggregation: 32 lanes/node, serial edges -----
// WF32: write fp32 out[HC]; WBF: write bf16 outb[HC].
template <bool WF32, bool WBF>
__global__ __launch_bounds__(256) void agg_dual_k(
    const int* __restrict__ rs0, const int* __restrict__ csr0,
    const ushort* __restrict__ hsb0, const float* __restrict__ atts0,
    const float* __restrict__ attd0, const float* __restrict__ bias0,
    float* __restrict__ out0, ushort* __restrict__ outb0, int n0,
    const int* __restrict__ rs1, const int* __restrict__ csr1,
    const ushort* __restrict__ hsb1, const float* __restrict__ atts1,
    const float* __restrict__ attd1, const float* __restrict__ bias1,
    float* __restrict__ out1, ushort* __restrict__ outb1, int n1) {
    int g = (int)((blockIdx.x * 256u + threadIdx.x) >> 5);
    const int* rs; const int* csr; const ushort* hsb; const float* atts;
    const float* attd; const float* bias; float* out; ushort* outb; int node;
    if (g < n0) {
        rs = rs0; csr = csr0; hsb = hsb0; atts = atts0; attd = attd0;
        bias = bias0; out = out0; outb = outb0; node = g;
    } else {
        node = g - n0;
        if (node >= n1) return;
        rs = rs1; csr = csr1; hsb = hsb1; atts = atts1; attd = attd1;
        bias = bias1; out = out1; outb = outb1;
    }
    int c = threadIdx.x & 31;    // channel group 4c..4c+3
    int h = c >> 3;              // head
    float ad = attd[node * 4 + h];
    int s0 = rs[node], s1 = rs[node + 1];
    float4 acc = make_float4(0.f, 0.f, 0.f, 0.f);
    float wsum = 0.f;
    int i = s0;
    for (; i + 4 <= s1; i += 4) {
        int sx[4];
        #pragma unroll
        for (int j = 0; j < 4; ++j) sx[j] = csr[i + j];
        ushort4 hv[4]; float el[4];
        #pragma unroll
        for (int j = 0; j < 4; ++j) {
            hv[j] = *reinterpret_cast<const ushort4*>(hsb + (size_t)sx[j] * HC + 4 * c);
            el[j] = atts[(size_t)sx[j] * 4 + h];
        }
        #pragma unroll
        for (int j = 0; j < 4; ++j) {
            float e = el[j] + ad;
            e = e > 0.f ? e : 0.2f * e;
            float w = __expf(e);
            wsum += w;
            acc.x = fmaf(w, bf2f(hv[j].x), acc.x);
            acc.y = fmaf(w, bf2f(hv[j].y), acc.y);
            acc.z = fmaf(w, bf2f(hv[j].z), acc.z);
            acc.w = fmaf(w, bf2f(hv[j].w), acc.w);
        }
    }
    for (; i < s1; ++i) {
        int src = csr[i];
        ushort4 hv = *reinterpret_cast<const ushort4*>(hsb + (size_t)src * HC + 4 * c);
        float e = atts[(size_t)src * 4 + h] + ad;
        e = e > 0.f ? e : 0.2f * e;
        float w = __expf(e);
        wsum += w;
        acc.x = fmaf(w, bf2f(hv.x), acc.x);
        acc.y = fmaf(w, bf2f(hv.y), acc.y);
        acc.z = fmaf(w, bf2f(hv.z), acc.z);
        acc.w = fmaf(w, bf2f(hv.w), acc.w);
    }
    float inv = 1.f / (wsum + 1e-16f);
    float4 b4 = reinterpret_cast<const float4*>(bias)[c];
    float4 v;
    v.x = fmaf(acc.x, inv, b4.x);
    v.y = fmaf(acc.y, inv, b4.y);
    v.z = fmaf(acc.z, inv, b4.z);
    v.w = fmaf(acc.w, inv, b4.w);
    v.x = v.x > 0.f ? v.x : 0.01f * v.x;
    v.y = v.y > 0.f ? v.y : 0.01f * v.y;
    v.z = v.z > 0.f ? v.z : 0.01f * v.z;
    v.w = v.w > 0.f ? v.w : 0.01f * v.w;
    if (WF32)
        reinterpret_cast<float4*>(out + (size_t)node * HC)[c] = v;
    if (WBF) {
        ushort4 vb;
        vb.x = (ushort)f2bf(v.x); vb.y = (ushort)f2bf(v.y);
        vb.z = (ushort)f2bf(v.z); vb.w = (ushort)f2bf(v.w);
        reinterpret_cast<ushort4*>(outb + (size_t)node * HC)[c] = vb;
    }
}

// ---------------------------------------------------------------------------
extern "C" void kernel_launch(void* const* d_in, const int* in_sizes, int n_in,
                              void* d_out, int out_size, void* d_ws, size_t ws_size,
                              hipStream_t stream) {
    const int Nu = in_sizes[0];
    const int Nm = in_sizes[1];
    const int E1 = in_sizes[2];   // um edges
    const int E2 = in_sizes[4];   // mu edges
    const int D  = in_sizes[6] / Nu;   // 64
    const int O  = in_sizes[27];       // 64

    const int*   user_ids  = (const int*)d_in[0];
    const int*   movie_ids = (const int*)d_in[1];
    const int*   um_src    = (const int*)d_in[2];
    const int*   um_dst    = (const int*)d_in[3];
    const int*   mu_src    = (const int*)d_in[4];
    const int*   mu_dst    = (const int*)d_in[5];
    const float* user_emb  = (const float*)d_in[6];
    const float* movie_emb = (const float*)d_in[7];
    const float* l1_um_Wsrc = (const float*)d_in[8];
    const float* l1_um_Wdst = (const float*)d_in[9];
    const float* l1_um_asrc = (const float*)d_in[10];
    const float* l1_um_adst = (const float*)d_in[11];
    const float* l1_um_b    = (const float*)d_in[12];
    const float* l1_mu_Wsrc = (const float*)d_in[13];
    const float* l1_mu_Wdst = (const float*)d_in[14];
    const float* l1_mu_asrc = (const float*)d_in[15];
    const float* l1_mu_adst = (const float*)d_in[16];
    const float* l1_mu_b    = (const float*)d_in[17];
    const float* l2_um_W    = (const float*)d_in[18];
    const float* l2_um_asrc = (const float*)d_in[19];
    const float* l2_um_adst = (const float*)d_in[20];
    const float* l2_um_b    = (const float*)d_in[21];
    const float* l2_mu_W    = (const float*)d_in[22];
    const float* l2_mu_asrc = (const float*)d_in[23];
    const float* l2_mu_adst = (const float*)d_in[24];
    const float* l2_mu_b    = (const float*)d_in[25];
    const float* Wo         = (const float*)d_in[26];
    const float* bo         = (const float*)d_in[27];

    // ---- workspace carve ----
    char* p = (char*)d_ws;
    auto alloc = [&](size_t bytes) { void* r = p; p += (bytes + 255) & ~(size_t)255; return r; };
    ushort* hs_u = (ushort*)alloc((size_t)Nu * HC * 2);
    ushort* hs_m = (ushort*)alloc((size_t)Nm * HC * 2);
    ushort* XUb  = (ushort*)alloc((size_t)Nu * HC * 2);
    ushort* XMb  = (ushort*)alloc((size_t)Nm * HC * 2);
    float* atts_u = (float*)alloc((size_t)Nu * 4 * 4);
    float* attd_u = (float*)alloc((size_t)Nu * 4 * 4);
    float* atts_m = (float*)alloc((size_t)Nm * 4 * 4);
    float* attd_m = (float*)alloc((size_t)Nm * 4 * 4);
    float* V_u1  = (float*)alloc((size_t)HC * 8 * 4);
    float* V_m1  = (float*)alloc((size_t)HC * 8 * 4);
    float* V_u2  = (float*)alloc((size_t)HC * 8 * 4);
    float* V_m2  = (float*)alloc((size_t)HC * 8 * 4);
    ushort* Wb_u1 = (ushort*)alloc((size_t)144 * D * 2);
    ushort* Wb_m1 = (ushort*)alloc((size_t)144 * D * 2);
    ushort* Wb_u2 = (ushort*)alloc((size_t)144 * HC * 2);
    ushort* Wb_m2 = (ushort*)alloc((size_t)144 * HC * 2);
    ushort* Wb_o  = (ushort*)alloc((size_t)64 * HC * 2);
    int* um_rs  = (int*)alloc((size_t)(Nm + 1) * 4);
    int* mu_rs  = (int*)alloc((size_t)(Nu + 1) * 4);
    int* cnts   = (int*)alloc((size_t)(Nm + Nu) * 4);   // um_cnt | mu_cnt
    int* um_cnt = cnts;
    int* mu_cnt = cnts + Nm;
    int* um_csr = (int*)alloc((size_t)E1 * 4);
    int* mu_csr = (int*)alloc((size_t)E2 * 4);
    int* partM  = (int*)alloc(512 * 4);
    int* partU  = (int*)alloc(512 * 4);

    auto cdiv = [](int a, int b) { return (a + b - 1) / b; };

    // ---- fold attention + pack weights (x-independent) ----
    {
        VT vt;
        const float* Ws[8] = {l1_um_Wsrc, l1_mu_Wdst, l1_mu_Wsrc, l1_um_Wdst,
                              l2_um_W, l2_mu_W, l2_mu_W, l2_um_W};
        const float* as[8] = {l1_um_asrc, l1_mu_adst, l1_mu_asrc, l1_um_adst,
                              l2_um_asrc, l2_mu_adst, l2_mu_asrc, l2_um_adst};
        float* vs[8] = {V_u1, V_u1, V_m1, V_m1, V_u2, V_u2, V_m2, V_m2};
        for (int i = 0; i < 8; ++i) { vt.W[i] = Ws[i]; vt.a[i] = as[i]; vt.v[i] = vs[i]; }
        make_v_all_k<<<12, 256, 0, stream>>>(vt);

        PT pt;
        const float* pW[5] = {l1_um_Wsrc, l1_mu_Wsrc, l2_um_W, l2_mu_W, Wo};
        const float* pV[5] = {V_u1, V_m1, V_u2, V_m2, nullptr};
        ushort* pB[5] = {Wb_u1, Wb_m1, Wb_u2, Wb_m2, Wb_o};
        int pK[5] = {D, D, HC, HC, HC};
        int pN[5] = {HC, HC, HC, HC, 64};
        int cum = 0;
        for (int i = 0; i < 5; ++i) {
            pt.W[i] = pW[i]; pt.V[i] = pV[i]; pt.Wb[i] = pB[i];
            pt.K[i] = pK[i]; pt.Nw[i] = pN[i];
            pt.start[i] = cum;
            cum += (i < 4 ? 144 : 64) * pK[i];
        }
        pt.start[5] = cum;
        pack_all_k<<<cdiv(cum, 256), 256, 0, stream>>>(pt);
    }

    // ---- CSR build (both edge types, reused by both layers) ----
    int nbM = cdiv(Nm + 1, 256), nbU = cdiv(Nu + 1, 256);
    hipMemsetAsync(cnts, 0, (size_t)(Nm + Nu) * 4, stream);
    hist_dual_k<<<cdiv(E1 + E2, 256), 256, 0, stream>>>(um_dst, um_cnt, E1, mu_dst, mu_cnt, E2);
    scan_block_dual_k<<<nbM + nbU, 256, 0, stream>>>(um_cnt, Nm, um_rs, partM, nbM,
                                                     mu_cnt, Nu, mu_rs, partU);
    scan_partial_dual_k<<<1, 512, 0, stream>>>(partM, nbM, partU, nbU);
    add_off_dual_k<<<nbM + nbU, 256, 0, stream>>>(um_rs, partM, Nm + 1, nbM,
                                                  mu_rs, partU, Nu + 1);
    hipMemsetAsync(cnts, 0, (size_t)(Nm + Nu) * 4, stream);
    fill_dual_k<<<cdiv(E1 + E2, 256), 256, 0, stream>>>(
        um_src, um_dst, um_rs, um_cnt, um_csr, E1,
        mu_src, mu_dst, mu_rs, mu_cnt, mu_csr, E2);

    // output slots: [out_user | out_movie | xu | xm]
    float* OU = (float*)d_out;
    float* OM = OU + (size_t)Nu * O;
    float* XU = OM + (size_t)Nm * O;
    float* XM = XU + (size_t)Nu * HC;

    int gbU = cdiv(Nu, 128), gbM = cdiv(Nm, 128);
    int aggBlocks = cdiv((Nm + Nu) * 32, 256);

    // ---- layer 1: A = fp32 embeddings (gathered), K = D ----
    gemm_dual_k<9, 0, false><<<gbU + gbM, 256, 0, stream>>>(
        user_emb, user_ids, Wb_u1, hs_u, atts_u, attd_u, nullptr, Nu, gbU,
        movie_emb, movie_ids, Wb_m1, hs_m, atts_m, attd_m, nullptr, Nm,
        nullptr, D, 0);
    // layer-1 agg: only bf16 activations needed (fp32 slot overwritten by L2)
    agg_dual_k<false, true><<<aggBlocks, 256, 0, stream>>>(
        um_rs, um_csr, hs_u, atts_u, attd_m, l1_um_b, nullptr, XMb, Nm,
        mu_rs, mu_csr, hs_m, atts_m, attd_u, l1_mu_b, nullptr, XUb, Nu);

    // ---- layer 2: A = bf16 activations, K = HC ----
    gemm_dual_k<9, 0, true><<<gbU + gbM, 256, 0, stream>>>(
        XUb, nullptr, Wb_u2, hs_u, atts_u, attd_u, nullptr, Nu, gbU,
        XMb, nullptr, Wb_m2, hs_m, atts_m, attd_m, nullptr, Nm,
        nullptr, HC, 0);
    // layer-2 agg: only fp32 (xu/xm are outputs; proj reads fp32)
    agg_dual_k<true, false><<<aggBlocks, 256, 0, stream>>>(
        um_rs, um_csr, hs_u, atts_u, attd_m, l2_um_b, XM, nullptr, Nm,
        mu_rs, mu_csr, hs_m, atts_m, attd_u, l2_mu_b, XU, nullptr, Nu);

    // ---- final projection: out = x @ Wo + bo (fp32 A) ----
    gemm_dual_k<4, 1, false><<<gbU + gbM, 256, 0, stream>>>(
        XU, nullptr, Wb_o, nullptr, nullptr, nullptr, OU, Nu, gbU,
        XM, nullptr, Wb_o, nullptr, nullptr, nullptr, OM, Nm,
        bo, HC, O);
}

// Round 6
// 271.254 us; speedup vs baseline: 2.5815x; 1.0927x over previous
//
#include <hip/hip_runtime.h>
#include <hip/hip_bf16.h>
#include <cstdint>

// ---------------------------------------------------------------------------
// HGAT: 2-layer hetero GAT (user<->movie), H=4 heads, C=32, HC=128.
// GEMMs on bf16 MFMA 16x16x32, fp32 accumulate. hs stored bf16 as ALIGNED
// 256B rows (4 cache lines/edge gather). Folded attention logits in separate
// fp32 [N,4] arrays. CSR build: hist's atomicAdd return value IS the edge's
// within-dst rank (stored sequentially) -> fill needs NO atomics; fill is
// dst-windowed (grid.y = 4) so the active csr write region is ~1MB and
// scattered 4B writes coalesce into full lines in L2 (kills the 16x write
// amplification seen in rocprof: WRITE 62MB for a 4MB payload).
// Edge pass (CSR by dst, 32 lanes/node): out[d] = (sum_e w_e*hs[src]) /
// (sum_e w_e) + b with w = exp(lrelu02(as[src]+ad[d])); lrelu01 after.
// Softmax max-subtraction skipped (logits bounded; shift-invariant; validated).
// ---------------------------------------------------------------------------

#define HC 128
#define HH 4
#define NWIN 4   // fill scatter windows

typedef __attribute__((ext_vector_type(8))) short bf16x8;
typedef __attribute__((ext_vector_type(4))) float f32x4;

__device__ __forceinline__ short f2bf(float f) {
    return __builtin_bit_cast(short, __float2bfloat16(f));
}
__device__ __forceinline__ float bf2f(ushort u) {
    return __builtin_bit_cast(float, ((unsigned)u) << 16);
}

// ---------------- fold attention: v[k, coff+h] = sum_c W[k,h*32+c]*a[h,c] ---
struct VT { const float* W[8]; const float* a[8]; float* v[8]; };
__global__ void make_v_all_k(VT t) {
    int gid = blockIdx.x * 256 + threadIdx.x;
    int task, base;
    if (gid < 1024) { task = gid >> 8; base = gid & 255; }
    else if (gid < 3072) { int g = gid - 1024; task = 4 + (g >> 9); base = g & 511; }
    else return;
    int k = base >> 2, h = base & 3;
    int coff = (task & 1) * 4;
    const float* wr = t.W[task] + (size_t)k * HC + h * 32;
    const float* ar = t.a[task] + h * 32;
    float s = 0.f;
    #pragma unroll
    for (int c = 0; c < 32; ++c) s = fmaf(wr[c], ar[c], s);
    t.v[task][k * 8 + coff + h] = s;
}

// ---------------- pack Wb[n][k] = bf16(W[k][n]); rows Nw..Nw+7 = V ----------
struct PT { const float* W[5]; const float* V[5]; ushort* Wb[5];
            int K[5]; int Nw[5]; int start[6]; };
__global__ void pack_all_k(PT t) {
    int gid = blockIdx.x * 256 + threadIdx.x;
    if (gid >= t.start[5]) return;
    int task = 0;
    while (gid >= t.start[task + 1]) ++task;
    int loc = gid - t.start[task];
    int K = t.K[task], Nw = t.Nw[task];
    int n = loc / K, k = loc % K;
    float v = 0.f;
    if (n < Nw) v = t.W[task][(size_t)k * Nw + n];
    else if (t.V[task] != nullptr && n < Nw + 8) v = t.V[task][k * 8 + (n - Nw)];
    t.Wb[task][loc] = (ushort)f2bf(v);
}

// ---------------- dual-segment bf16 MFMA GEMM -------------------------------
// MODE 0: hs out (bf16 [M,128]) + atts fp32 [M,4] + attd fp32 [M,4].
// MODE 1: fp32 C[M,ldc] + bias. ABF: A is dense bf16 (ushort), else fp32+idx.
template <int NT, int MODE, bool ABF>
__global__ __launch_bounds__(256) void gemm_dual_k(
    const void* A0, const int* idx0, const ushort* Wb0, ushort* hsb0,
    float* atts0, float* attd0, float* C0, int M0, int nb0,
    const void* A1, const int* idx1, const ushort* Wb1, ushort* hsb1,
    float* atts1, float* attd1, float* C1, int M1,
    const float* bias, int K, int ldc) {
    const void* A; const int* aidx; const ushort* Wb; ushort* hsb;
    float* atts; float* attd; float* C; int M, bid;
    if ((int)blockIdx.x < nb0) {
        A = A0; aidx = idx0; Wb = Wb0; hsb = hsb0; atts = atts0; attd = attd0;
        C = C0; M = M0; bid = blockIdx.x;
    } else {
        A = A1; aidx = idx1; Wb = Wb1; hsb = hsb1; atts = atts1; attd = attd1;
        C = C1; M = M1; bid = blockIdx.x - nb0;
    }
    int lane = threadIdx.x & 63;
    int wave = threadIdx.x >> 6;
    int m_base = bid * 128 + wave * 32;
    int lm = lane & 15;      // A row-in-tile / C col-in-tile
    int kg = lane >> 4;      // k-group (8 consecutive k)

    int r0 = m_base + lm, r1 = r0 + 16;
    int cr0 = r0 < M ? r0 : M - 1;
    int cr1 = r1 < M ? r1 : M - 1;
    int row0 = aidx ? aidx[cr0] : cr0;
    int row1 = aidx ? aidx[cr1] : cr1;
    const ushort* bp = Wb + (size_t)lm * K + kg * 8;

    f32x4 acc[2][NT] = {};
    for (int k0 = 0; k0 < K; k0 += 32) {
        bf16x8 a[2];
        if (ABF) {
            const ushort* a0p = (const ushort*)A + (size_t)row0 * K + kg * 8;
            const ushort* a1p = (const ushort*)A + (size_t)row1 * K + kg * 8;
            a[0] = *reinterpret_cast<const bf16x8*>(a0p + k0);
            a[1] = *reinterpret_cast<const bf16x8*>(a1p + k0);
        } else {
            const float* a0p = (const float*)A + (size_t)row0 * K + kg * 8;
            const float* a1p = (const float*)A + (size_t)row1 * K + kg * 8;
            float af[2][8];
            *reinterpret_cast<float4*>(&af[0][0]) = *reinterpret_cast<const float4*>(a0p + k0);
            *reinterpret_cast<float4*>(&af[0][4]) = *reinterpret_cast<const float4*>(a0p + k0 + 4);
            *reinterpret_cast<float4*>(&af[1][0]) = *reinterpret_cast<const float4*>(a1p + k0);
            *reinterpret_cast<float4*>(&af[1][4]) = *reinterpret_cast<const float4*>(a1p + k0 + 4);
            #pragma unroll
            for (int mi = 0; mi < 2; ++mi)
                #pragma unroll
                for (int j = 0; j < 8; ++j) a[mi][j] = f2bf(af[mi][j]);
        }
        #pragma unroll
        for (int nt = 0; nt < NT; ++nt) {
            bf16x8 b = *reinterpret_cast<const bf16x8*>(bp + (size_t)nt * 16 * K + k0);
            acc[0][nt] = __builtin_amdgcn_mfma_f32_16x16x32_bf16(a[0], b, acc[0][nt], 0, 0, 0);
            acc[1][nt] = __builtin_amdgcn_mfma_f32_16x16x32_bf16(a[1], b, acc[1][nt], 0, 0, 0);
        }
    }
    #pragma unroll
    for (int mi = 0; mi < 2; ++mi) {
        int rowb = m_base + mi * 16 + kg * 4;
        if (MODE == 0) {
            #pragma unroll
            for (int nt = 0; nt < NT - 1; ++nt) {
                int col = nt * 16 + lm;
                #pragma unroll
                for (int r = 0; r < 4; ++r) {
                    int row = rowb + r;
                    if (row < M) hsb[(size_t)row * HC + col] = (ushort)f2bf(acc[mi][nt][r]);
                }
            }
            #pragma unroll
            for (int r = 0; r < 4; ++r) {
                int row = rowb + r;
                if (row < M) {
                    float v = acc[mi][NT - 1][r];
                    if (lm < 4) atts[(size_t)row * 4 + lm] = v;
                    else if (lm < 8) attd[(size_t)row * 4 + (lm - 4)] = v;
                }
            }
        } else {
            #pragma unroll
            for (int nt = 0; nt < NT; ++nt) {
                int col = nt * 16 + lm;
                float bv = bias[col];
                #pragma unroll
                for (int r = 0; r < 4; ++r) {
                    int row = rowb + r;
                    if (row < M) C[(size_t)row * ldc + col] = acc[mi][nt][r] + bv;
                }
            }
        }
    }
}

// ---------------- CSR build (dual edge-type) --------------------------------
// hist also emits rank[e] = old count = edge's within-dst slot (coalesced).
__global__ void hist_dual_k(const int* __restrict__ d0, int* __restrict__ c0, int E0,
                            const int* __restrict__ d1, int* __restrict__ c1, int E1,
                            int* __restrict__ rank) {
    int e = blockIdx.x * 256 + threadIdx.x;
    if (e < E0) rank[e] = atomicAdd(&c0[d0[e]], 1);
    else if (e - E0 < E1) rank[e] = atomicAdd(&c1[d1[e - E0]], 1);
}

__device__ __forceinline__ void scan_block_body(
    const int* deg, int n, int len, int* out, int* partial, int b) {
    __shared__ int s[256];
    int i = b * 256 + threadIdx.x;
    int v = (i < n) ? deg[i] : 0;
    s[threadIdx.x] = v;
    __syncthreads();
    for (int off = 1; off < 256; off <<= 1) {
        int t = (threadIdx.x >= off) ? s[threadIdx.x - off] : 0;
        __syncthreads();
        s[threadIdx.x] += t;
        __syncthreads();
    }
    if (i < len) out[i] = s[threadIdx.x] - v;
    if (threadIdx.x == 255) partial[b] = s[255];
}

__global__ void scan_block_dual_k(const int* dM, int nM, int* rsM, int* pM, int nbM,
                                  const int* dU, int nU, int* rsU, int* pU) {
    if ((int)blockIdx.x < nbM)
        scan_block_body(dM, nM, nM + 1, rsM, pM, blockIdx.x);
    else
        scan_block_body(dU, nU, nU + 1, rsU, pU, blockIdx.x - nbM);
}

__global__ void scan_partial_dual_k(int* pM, int nbM, int* pU, int nbU) {
    __shared__ int s[512];
    int t = threadIdx.x;
    for (int seg = 0; seg < 2; ++seg) {
        int* p = seg ? pU : pM;
        int nb = seg ? nbU : nbM;
        int v = (t < nb) ? p[t] : 0;
        s[t] = v;
        __syncthreads();
        for (int off = 1; off < 512; off <<= 1) {
            int x = (t >= off) ? s[t - off] : 0;
            __syncthreads();
            s[t] += x;
            __syncthreads();
        }
        if (t < nb) p[t] = s[t] - v;
        __syncthreads();
    }
}

__global__ void add_off_dual_k(int* __restrict__ oM, const int* __restrict__ pM,
                               int lenM, int nbM,
                               int* __restrict__ oU, const int* __restrict__ pU,
                               int lenU) {
    int b = blockIdx.x;
    if (b < nbM) {
        int i = b * 256 + threadIdx.x;
        if (i < lenM) oM[i] += pM[b];
    } else {
        b -= nbM;
        int i = b * 256 + threadIdx.x;
        if (i < lenU) oU[i] += pU[b];
    }
}

// atomic-free, dst-windowed scatter: window w handles dst in [w*n/NWIN, ...).
__global__ void fill_dual_k(const int* __restrict__ s0, const int* __restrict__ d0,
                            const int* __restrict__ rs0, int* __restrict__ csr0,
                            int E0, int n0,
                            const int* __restrict__ s1, const int* __restrict__ d1,
                            const int* __restrict__ rs1, int* __restrict__ csr1,
                            int E1, int n1,
                            const int* __restrict__ rank) {
    int e = blockIdx.x * 256 + threadIdx.x;
    int w = blockIdx.y;
    if (e < E0) {
        int d = d0[e];
        int lo = (int)((long)w * n0 / NWIN), hi = (int)((long)(w + 1) * n0 / NWIN);
        if (d >= lo && d < hi) csr0[rs0[d] + rank[e]] = s0[e];
    } else if (e - E0 < E1) {
        int e1 = e - E0;
        int d = d1[e1];
        int lo = (int)((long)w * n1 / NWIN), hi = (int)((long)(w + 1) * n1 / NWIN);
        if (d >= lo && d < hi) csr1[rs1[d] + rank[e]] = s1[e1];
    }
}

// ---------------- dual per-dst aggregation: 32 lanes/node, serial edges -----
// WF32: write fp32 out[HC]; WBF: write bf16 outb[HC].
template <bool WF32, bool WBF>
__global__ __launch_bounds__(256) void agg_dual_k(
    const int* __restrict__ rs0, const int* __restrict__ csr0,
    const ushort* __restrict__ hsb0, const float* __restrict__ atts0,
    const float* __restrict__ attd0, const float* __restrict__ bias0,
    float* __restrict__ out0, ushort* __restrict__ outb0, int n0,
    const int* __restrict__ rs1, const int* __restrict__ csr1,
    const ushort* __restrict__ hsb1, const float* __restrict__ atts1,
    const float* __restrict__ attd1, const float* __restrict__ bias1,
    float* __restrict__ out1, ushort* __restrict__ outb1, int n1) {
    int g = (int)((blockIdx.x * 256u + threadIdx.x) >> 5);
    const int* rs; const int* csr; const ushort* hsb; const float* atts;
    const float* attd; const float* bias; float* out; ushort* outb; int node;
    if (g < n0) {
        rs = rs0; csr = csr0; hsb = hsb0; atts = atts0; attd = attd0;
        bias = bias0; out = out0; outb = outb0; node = g;
    } else {
        node = g - n0;
        if (node >= n1) return;
        rs = rs1; csr = csr1; hsb = hsb1; atts = atts1; attd = attd1;
        bias = bias1; out = out1; outb = outb1;
    }
    int c = threadIdx.x & 31;    // channel group 4c..4c+3
    int h = c >> 3;              // head
    float ad = attd[node * 4 + h];
    int s0 = rs[node], s1 = rs[node + 1];
    float4 acc = make_float4(0.f, 0.f, 0.f, 0.f);
    float wsum = 0.f;
    int i = s0;
    for (; i + 8 <= s1; i += 8) {           // 8 gathers in flight
        int sx[8];
        #pragma unroll
        for (int j = 0; j < 8; ++j) sx[j] = csr[i + j];
        ushort4 hv[8]; float el[8];
        #pragma unroll
        for (int j = 0; j < 8; ++j) {
            hv[j] = *reinterpret_cast<const ushort4*>(hsb + (size_t)sx[j] * HC + 4 * c);
            el[j] = atts[(size_t)sx[j] * 4 + h];
        }
        #pragma unroll
        for (int j = 0; j < 8; ++j) {
            float e = el[j] + ad;
            e = e > 0.f ? e : 0.2f * e;
            float w = __expf(e);
            wsum += w;
            acc.x = fmaf(w, bf2f(hv[j].x), acc.x);
            acc.y = fmaf(w, bf2f(hv[j].y), acc.y);
            acc.z = fmaf(w, bf2f(hv[j].z), acc.z);
            acc.w = fmaf(w, bf2f(hv[j].w), acc.w);
        }
    }
    for (; i + 4 <= s1; i += 4) {
        int sx[4];
        #pragma unroll
        for (int j = 0; j < 4; ++j) sx[j] = csr[i + j];
        ushort4 hv[4]; float el[4];
        #pragma unroll
        for (int j = 0; j < 4; ++j) {
            hv[j] = *reinterpret_cast<const ushort4*>(hsb + (size_t)sx[j] * HC + 4 * c);
            el[j] = atts[(size_t)sx[j] * 4 + h];
        }
        #pragma unroll
        for (int j = 0; j < 4; ++j) {
            float e = el[j] + ad;
            e = e > 0.f ? e : 0.2f * e;
            float w = __expf(e);
            wsum += w;
            acc.x = fmaf(w, bf2f(hv[j].x), acc.x);
            acc.y = fmaf(w, bf2f(hv[j].y), acc.y);
            acc.z = fmaf(w, bf2f(hv[j].z), acc.z);
            acc.w = fmaf(w, bf2f(hv[j].w), acc.w);
        }
    }
    for (; i < s1; ++i) {
        int src = csr[i];
        ushort4 hv = *reinterpret_cast<const ushort4*>(hsb + (size_t)src * HC + 4 * c);
        float e = atts[(size_t)src * 4 + h] + ad;
        e = e > 0.f ? e : 0.2f * e;
        float w = __expf(e);
        wsum += w;
        acc.x = fmaf(w, bf2f(hv.x), acc.x);
        acc.y = fmaf(w, bf2f(hv.y), acc.y);
        acc.z = fmaf(w, bf2f(hv.z), acc.z);
        acc.w = fmaf(w, bf2f(hv.w), acc.w);
    }
    float inv = 1.f / (wsum + 1e-16f);
    float4 b4 = reinterpret_cast<const float4*>(bias)[c];
    float4 v;
    v.x = fmaf(acc.x, inv, b4.x);
    v.y = fmaf(acc.y, inv, b4.y);
    v.z = fmaf(acc.z, inv, b4.z);
    v.w = fmaf(acc.w, inv, b4.w);
    v.x = v.x > 0.f ? v.x : 0.01f * v.x;
    v.y = v.y > 0.f ? v.y : 0.01f * v.y;
    v.z = v.z > 0.f ? v.z : 0.01f * v.z;
    v.w = v.w > 0.f ? v.w : 0.01f * v.w;
    if (WF32)
        reinterpret_cast<float4*>(out + (size_t)node * HC)[c] = v;
    if (WBF) {
        ushort4 vb;
        vb.x = (ushort)f2bf(v.x); vb.y = (ushort)f2bf(v.y);
        vb.z = (ushort)f2bf(v.z); vb.w = (ushort)f2bf(v.w);
        reinterpret_cast<ushort4*>(outb + (size_t)node * HC)[c] = vb;
    }
}

// ---------------------------------------------------------------------------
extern "C" void kernel_launch(void* const* d_in, const int* in_sizes, int n_in,
                              void* d_out, int out_size, void* d_ws, size_t ws_size,
                              hipStream_t stream) {
    const int Nu = in_sizes[0];
    const int Nm = in_sizes[1];
    const int E1 = in_sizes[2];   // um edges
    const int E2 = in_sizes[4];   // mu edges
    const int D  = in_sizes[6] / Nu;   // 64
    const int O  = in_sizes[27];       // 64

    const int*   user_ids  = (const int*)d_in[0];
    const int*   movie_ids = (const int*)d_in[1];
    const int*   um_src    = (const int*)d_in[2];
    const int*   um_dst    = (const int*)d_in[3];
    const int*   mu_src    = (const int*)d_in[4];
    const int*   mu_dst    = (const int*)d_in[5];
    const float* user_emb  = (const float*)d_in[6];
    const float* movie_emb = (const float*)d_in[7];
    const float* l1_um_Wsrc = (const float*)d_in[8];
    const float* l1_um_Wdst = (const float*)d_in[9];
    const float* l1_um_asrc = (const float*)d_in[10];
    const float* l1_um_adst = (const float*)d_in[11];
    const float* l1_um_b    = (const float*)d_in[12];
    const float* l1_mu_Wsrc = (const float*)d_in[13];
    const float* l1_mu_Wdst = (const float*)d_in[14];
    const float* l1_mu_asrc = (const float*)d_in[15];
    const float* l1_mu_adst = (const float*)d_in[16];
    const float* l1_mu_b    = (const float*)d_in[17];
    const float* l2_um_W    = (const float*)d_in[18];
    const float* l2_um_asrc = (const float*)d_in[19];
    const float* l2_um_adst = (const float*)d_in[20];
    const float* l2_um_b    = (const float*)d_in[21];
    const float* l2_mu_W    = (const float*)d_in[22];
    const float* l2_mu_asrc = (const float*)d_in[23];
    const float* l2_mu_adst = (const float*)d_in[24];
    const float* l2_mu_b    = (const float*)d_in[25];
    const float* Wo         = (const float*)d_in[26];
    const float* bo         = (const float*)d_in[27];

    // ---- workspace carve ----
    char* p = (char*)d_ws;
    auto alloc = [&](size_t bytes) { void* r = p; p += (bytes + 255) & ~(size_t)255; return r; };
    ushort* hs_u = (ushort*)alloc((size_t)Nu * HC * 2);
    ushort* hs_m = (ushort*)alloc((size_t)Nm * HC * 2);
    ushort* XUb  = (ushort*)alloc((size_t)Nu * HC * 2);
    ushort* XMb  = (ushort*)alloc((size_t)Nm * HC * 2);
    float* atts_u = (float*)alloc((size_t)Nu * 4 * 4);
    float* attd_u = (float*)alloc((size_t)Nu * 4 * 4);
    float* atts_m = (float*)alloc((size_t)Nm * 4 * 4);
    float* attd_m = (float*)alloc((size_t)Nm * 4 * 4);
    float* V_u1  = (float*)alloc((size_t)HC * 8 * 4);
    float* V_m1  = (float*)alloc((size_t)HC * 8 * 4);
    float* V_u2  = (float*)alloc((size_t)HC * 8 * 4);
    float* V_m2  = (float*)alloc((size_t)HC * 8 * 4);
    ushort* Wb_u1 = (ushort*)alloc((size_t)144 * D * 2);
    ushort* Wb_m1 = (ushort*)alloc((size_t)144 * D * 2);
    ushort* Wb_u2 = (ushort*)alloc((size_t)144 * HC * 2);
    ushort* Wb_m2 = (ushort*)alloc((size_t)144 * HC * 2);
    ushort* Wb_o  = (ushort*)alloc((size_t)64 * HC * 2);
    int* um_rs  = (int*)alloc((size_t)(Nm + 1) * 4);
    int* mu_rs  = (int*)alloc((size_t)(Nu + 1) * 4);
    int* cnts   = (int*)alloc((size_t)(Nm + Nu) * 4);   // um_cnt | mu_cnt
    int* um_cnt = cnts;
    int* mu_cnt = cnts + Nm;
    int* um_csr = (int*)alloc((size_t)E1 * 4);
    int* mu_csr = (int*)alloc((size_t)E2 * 4);
    int* rank   = (int*)alloc((size_t)(E1 + E2) * 4);
    int* partM  = (int*)alloc(512 * 4);
    int* partU  = (int*)alloc(512 * 4);

    auto cdiv = [](int a, int b) { return (a + b - 1) / b; };

    // ---- fold attention + pack weights (x-independent) ----
    {
        VT vt;
        const float* Ws[8] = {l1_um_Wsrc, l1_mu_Wdst, l1_mu_Wsrc, l1_um_Wdst,
                              l2_um_W, l2_mu_W, l2_mu_W, l2_um_W};
        const float* as[8] = {l1_um_asrc, l1_mu_adst, l1_mu_asrc, l1_um_adst,
                              l2_um_asrc, l2_mu_adst, l2_mu_asrc, l2_um_adst};
        float* vs[8] = {V_u1, V_u1, V_m1, V_m1, V_u2, V_u2, V_m2, V_m2};
        for (int i = 0; i < 8; ++i) { vt.W[i] = Ws[i]; vt.a[i] = as[i]; vt.v[i] = vs[i]; }
        make_v_all_k<<<12, 256, 0, stream>>>(vt);

        PT pt;
        const float* pW[5] = {l1_um_Wsrc, l1_mu_Wsrc, l2_um_W, l2_mu_W, Wo};
        const float* pV[5] = {V_u1, V_m1, V_u2, V_m2, nullptr};
        ushort* pB[5] = {Wb_u1, Wb_m1, Wb_u2, Wb_m2, Wb_o};
        int pK[5] = {D, D, HC, HC, HC};
        int pN[5] = {HC, HC, HC, HC, 64};
        int cum = 0;
        for (int i = 0; i < 5; ++i) {
            pt.W[i] = pW[i]; pt.V[i] = pV[i]; pt.Wb[i] = pB[i];
            pt.K[i] = pK[i]; pt.Nw[i] = pN[i];
            pt.start[i] = cum;
            cum += (i < 4 ? 144 : 64) * pK[i];
        }
        pt.start[5] = cum;
        pack_all_k<<<cdiv(cum, 256), 256, 0, stream>>>(pt);
    }

    // ---- CSR build (both edge types, reused by both layers) ----
    int nbM = cdiv(Nm + 1, 256), nbU = cdiv(Nu + 1, 256);
    hipMemsetAsync(cnts, 0, (size_t)(Nm + Nu) * 4, stream);
    hist_dual_k<<<cdiv(E1 + E2, 256), 256, 0, stream>>>(
        um_dst, um_cnt, E1, mu_dst, mu_cnt, E2, rank);
    scan_block_dual_k<<<nbM + nbU, 256, 0, stream>>>(um_cnt, Nm, um_rs, partM, nbM,
                                                     mu_cnt, Nu, mu_rs, partU);
    scan_partial_dual_k<<<1, 512, 0, stream>>>(partM, nbM, partU, nbU);
    add_off_dual_k<<<nbM + nbU, 256, 0, stream>>>(um_rs, partM, Nm + 1, nbM,
                                                  mu_rs, partU, Nu + 1);
    {
        dim3 g(cdiv(E1 + E2, 256), NWIN);
        fill_dual_k<<<g, 256, 0, stream>>>(
            um_src, um_dst, um_rs, um_csr, E1, Nm,
            mu_src, mu_dst, mu_rs, mu_csr, E2, Nu, rank);
    }

    // output slots: [out_user | out_movie | xu | xm]
    float* OU = (float*)d_out;
    float* OM = OU + (size_t)Nu * O;
    float* XU = OM + (size_t)Nm * O;
    float* XM = XU + (size_t)Nu * HC;

    int gbU = cdiv(Nu, 128), gbM = cdiv(Nm, 128);
    int aggBlocks = cdiv((Nm + Nu) * 32, 256);

    // ---- layer 1: A = fp32 embeddings (gathered), K = D ----
    gemm_dual_k<9, 0, false><<<gbU + gbM, 256, 0, stream>>>(
        user_emb, user_ids, Wb_u1, hs_u, atts_u, attd_u, nullptr, Nu, gbU,
        movie_emb, movie_ids, Wb_m1, hs_m, atts_m, attd_m, nullptr, Nm,
        nullptr, D, 0);
    // layer-1 agg: only bf16 activations needed (fp32 slot overwritten by L2)
    agg_dual_k<false, true><<<aggBlocks, 256, 0, stream>>>(
        um_rs, um_csr, hs_u, atts_u, attd_m, l1_um_b, nullptr, XMb, Nm,
        mu_rs, mu_csr, hs_m, atts_m, attd_u, l1_mu_b, nullptr, XUb, Nu);

    // ---- layer 2: A = bf16 activations, K = HC ----
    gemm_dual_k<9, 0, true><<<gbU + gbM, 256, 0, stream>>>(
        XUb, nullptr, Wb_u2, hs_u, atts_u, attd_u, nullptr, Nu, gbU,
        XMb, nullptr, Wb_m2, hs_m, atts_m, attd_m, nullptr, Nm,
        nullptr, HC, 0);
    // layer-2 agg: only fp32 (xu/xm are outputs; proj reads fp32)
    agg_dual_k<true, false><<<aggBlocks, 256, 0, stream>>>(
        um_rs, um_csr, hs_u, atts_u, attd_m, l2_um_b, XM, nullptr, Nm,
        mu_rs, mu_csr, hs_m, atts_m, attd_u, l2_mu_b, XU, nullptr, Nu);

    // ---- final projection: out = x @ Wo + bo (fp32 A) ----
    gemm_dual_k<4, 1, false><<<gbU + gbM, 256, 0, stream>>>(
        XU, nullptr, Wb_o, nullptr, nullptr, nullptr, OU, Nu, gbU,
        XM, nullptr, Wb_o, nullptr, nullptr, nullptr, OM, Nm,
        bo, HC, O);
}

// Round 7
// 270.715 us; speedup vs baseline: 2.5867x; 1.0020x over previous
//
#include <hip/hip_runtime.h>
#include <hip/hip_bf16.h>
#include <cstdint>

// ---------------------------------------------------------------------------
// HGAT: 2-layer hetero GAT (user<->movie), H=4 heads, C=32, HC=128.
// Layer 1 restructured via linearity: out = ((sum w*x_src)/sum w) @ Wsrc + b,
// so the edge pass gathers RAW 64-ch bf16 features (128B = 2 cache lines/edge,
// half the hs-gather traffic) and one dense MFMA GEMM transforms the
// aggregated rows (bias+lrelu fused). Attention logits computed in the
// fp32->bf16 conversion pass (x . V with 16-lane shuffle reduce).
// Layer 2 keeps gather-hs structure (rows already 128ch). All GEMMs bf16
// MFMA 16x16x32, fp32 accumulate. CSR: rank-from-hist (atomic-free fill),
// dst-windowed scatter (kills write amplification).
// agg kernels: 4-deep unroll (8-deep raised VGPR 28->40, occ 68->51%: slower).
// Softmax max-subtraction skipped (logits bounded; shift-invariant; validated).
// ---------------------------------------------------------------------------

#define HC 128
#define HH 4
#define NWIN 4   // fill scatter windows

typedef __attribute__((ext_vector_type(8))) short bf16x8;
typedef __attribute__((ext_vector_type(4))) float f32x4;

__device__ __forceinline__ short f2bf(float f) {
    return __builtin_bit_cast(short, __float2bfloat16(f));
}
__device__ __forceinline__ float bf2f(ushort u) {
    return __builtin_bit_cast(float, ((unsigned)u) << 16);
}

// ---------------- fold attention: v[k, coff+h] = sum_c W[k,h*32+c]*a[h,c] ---
struct VT { const float* W[8]; const float* a[8]; float* v[8]; };
__global__ void make_v_all_k(VT t) {
    int gid = blockIdx.x * 256 + threadIdx.x;
    int task, base;
    if (gid < 1024) { task = gid >> 8; base = gid & 255; }
    else if (gid < 3072) { int g = gid - 1024; task = 4 + (g >> 9); base = g & 511; }
    else return;
    int k = base >> 2, h = base & 3;
    int coff = (task & 1) * 4;
    const float* wr = t.W[task] + (size_t)k * HC + h * 32;
    const float* ar = t.a[task] + h * 32;
    float s = 0.f;
    #pragma unroll
    for (int c = 0; c < 32; ++c) s = fmaf(wr[c], ar[c], s);
    t.v[task][k * 8 + coff + h] = s;
}

// ---------------- pack Wb[n][k] = bf16(W[k][n]); rows Nw..Nw+7 = V ----------
struct PT { const float* W[5]; const float* V[5]; ushort* Wb[5];
            int K[5]; int Nw[5]; int start[6]; };
__global__ void pack_all_k(PT t) {
    int gid = blockIdx.x * 256 + threadIdx.x;
    if (gid >= t.start[5]) return;
    int task = 0;
    while (gid >= t.start[task + 1]) ++task;
    int loc = gid - t.start[task];
    int K = t.K[task], Nw = t.Nw[task];
    int n = loc / K, k = loc % K;
    float v = 0.f;
    if (n < Nw) v = t.W[task][(size_t)k * Nw + n];
    else if (t.V[task] != nullptr && n < Nw + 8) v = t.V[task][k * 8 + (n - Nw)];
    t.Wb[task][loc] = (ushort)f2bf(v);
}

// ---------------- convert emb->bf16 + per-node att logits (K=64) ------------
// 16 threads/node; s[0..7] = x . V[:,j]; lanes 0-3 -> atts, 4-7 -> attd.
__global__ __launch_bounds__(256) void conv_att_dual_k(
    const float* __restrict__ x0, const int* __restrict__ idx0,
    const float* __restrict__ V0, ushort* __restrict__ xe0,
    float* __restrict__ atts0, float* __restrict__ attd0, int M0,
    const float* __restrict__ x1, const int* __restrict__ idx1,
    const float* __restrict__ V1, ushort* __restrict__ xe1,
    float* __restrict__ atts1, float* __restrict__ attd1, int M1) {
    int slot = (int)((blockIdx.x * 256u + threadIdx.x) >> 4);
    int c = threadIdx.x & 15;
    const float* x; const int* idx; const float* V; ushort* xe;
    float* atts; float* attd; int node;
    if (slot < M0) {
        x = x0; idx = idx0; V = V0; xe = xe0; atts = atts0; attd = attd0; node = slot;
    } else {
        node = slot - M0;
        if (node >= M1) return;
        x = x1; idx = idx1; V = V1; xe = xe1; atts = atts1; attd = attd1;
    }
    int row = idx ? idx[node] : node;
    float4 v = *reinterpret_cast<const float4*>(&x[(size_t)row * 64 + c * 4]);
    ushort4 u;
    u.x = (ushort)f2bf(v.x); u.y = (ushort)f2bf(v.y);
    u.z = (ushort)f2bf(v.z); u.w = (ushort)f2bf(v.w);
    *reinterpret_cast<ushort4*>(&xe[(size_t)node * 64 + c * 4]) = u;
    float s[8];
    #pragma unroll
    for (int j = 0; j < 8; ++j) {
        s[j] = v.x * V[(c * 4 + 0) * 8 + j] + v.y * V[(c * 4 + 1) * 8 + j]
             + v.z * V[(c * 4 + 2) * 8 + j] + v.w * V[(c * 4 + 3) * 8 + j];
    }
    #pragma unroll
    for (int off = 1; off < 16; off <<= 1)
        #pragma unroll
        for (int j = 0; j < 8; ++j) s[j] += __shfl_xor(s[j], off);
    if (c < 4) atts[node * 4 + c] = s[c];
    else if (c < 8) attd[node * 4 + (c - 4)] = s[c];
}

// ---------------- layer-1 weighted-mean gather (64ch bf16, 16 lanes/node) ---
__global__ __launch_bounds__(256) void aggm_dual_k(
    const int* __restrict__ rs0, const int* __restrict__ csr0,
    const ushort* __restrict__ xe0, const float* __restrict__ atts0,
    const float* __restrict__ attd0, ushort* __restrict__ xagg0, int n0,
    const int* __restrict__ rs1, const int* __restrict__ csr1,
    const ushort* __restrict__ xe1, const float* __restrict__ atts1,
    const float* __restrict__ attd1, ushort* __restrict__ xagg1, int n1) {
    int g = (int)((blockIdx.x * 256u + threadIdx.x) >> 4);
    const int* rs; const int* csr; const ushort* xe; const float* atts;
    const float* attd; ushort* xagg; int node;
    if (g < n0) {
        rs = rs0; csr = csr0; xe = xe0; atts = atts0; attd = attd0;
        xagg = xagg0; node = g;
    } else {
        node = g - n0;
        if (node >= n1) return;
        rs = rs1; csr = csr1; xe = xe1; atts = atts1; attd = attd1;
        xagg = xagg1;
    }
    int c = threadIdx.x & 15;    // ushort4 group: channels 4c..4c+3
    int h = c >> 2;              // head (64ch = 4 heads x 16)
    float ad = attd[node * 4 + h];
    int s0 = rs[node], s1 = rs[node + 1];
    float4 acc = make_float4(0.f, 0.f, 0.f, 0.f);
    float wsum = 0.f;
    int i = s0;
    for (; i + 4 <= s1; i += 4) {
        int sx[4];
        #pragma unroll
        for (int j = 0; j < 4; ++j) sx[j] = csr[i + j];
        ushort4 hv[4]; float el[4];
        #pragma unroll
        for (int j = 0; j < 4; ++j) {
            hv[j] = *reinterpret_cast<const ushort4*>(xe + (size_t)sx[j] * 64 + 4 * c);
            el[j] = atts[(size_t)sx[j] * 4 + h];
        }
        #pragma unroll
        for (int j = 0; j < 4; ++j) {
            float e = el[j] + ad;
            e = e > 0.f ? e : 0.2f * e;
            float w = __expf(e);
            wsum += w;
            acc.x = fmaf(w, bf2f(hv[j].x), acc.x);
            acc.y = fmaf(w, bf2f(hv[j].y), acc.y);
            acc.z = fmaf(w, bf2f(hv[j].z), acc.z);
            acc.w = fmaf(w, bf2f(hv[j].w), acc.w);
        }
    }
    for (; i < s1; ++i) {
        int src = csr[i];
        ushort4 hv = *reinterpret_cast<const ushort4*>(xe + (size_t)src * 64 + 4 * c);
        float e = atts[(size_t)src * 4 + h] + ad;
        e = e > 0.f ? e : 0.2f * e;
        float w = __expf(e);
        wsum += w;
        acc.x = fmaf(w, bf2f(hv.x), acc.x);
        acc.y = fmaf(w, bf2f(hv.y), acc.y);
        acc.z = fmaf(w, bf2f(hv.z), acc.z);
        acc.w = fmaf(w, bf2f(hv.w), acc.w);
    }
    float inv = 1.f / (wsum + 1e-16f);
    ushort4 u;
    u.x = (ushort)f2bf(acc.x * inv); u.y = (ushort)f2bf(acc.y * inv);
    u.z = (ushort)f2bf(acc.z * inv); u.w = (ushort)f2bf(acc.w * inv);
    *reinterpret_cast<ushort4*>(xagg + (size_t)node * 64 + 4 * c) = u;
}

// ---------------- dual-segment bf16 MFMA GEMM -------------------------------
// MODE 0: hs out (bf16 [M,128]) + atts fp32 [M,4] + attd fp32 [M,4].
// MODE 1: fp32 C[M,ldc] + bias.
// MODE 3: bf16 hsb[M,128] = lrelu01(acc + bias)  (layer-1 transform).
// ABF: A is dense bf16 (ushort), else fp32 (+optional idx gather).
template <int NT, int MODE, bool ABF>
__global__ __launch_bounds__(256) void gemm_dual_k(
    const void* A0, const int* idx0, const ushort* Wb0, ushort* hsb0,
    float* atts0, float* attd0, float* C0, const float* bias0, int M0, int nb0,
    const void* A1, const int* idx1, const ushort* Wb1, ushort* hsb1,
    float* atts1, float* attd1, float* C1, const float* bias1, int M1,
    int K, int ldc) {
    const void* A; const int* aidx; const ushort* Wb; ushort* hsb;
    float* atts; float* attd; float* C; const float* bias; int M, bid;
    if ((int)blockIdx.x < nb0) {
        A = A0; aidx = idx0; Wb = Wb0; hsb = hsb0; atts = atts0; attd = attd0;
        C = C0; bias = bias0; M = M0; bid = blockIdx.x;
    } else {
        A = A1; aidx = idx1; Wb = Wb1; hsb = hsb1; atts = atts1; attd = attd1;
        C = C1; bias = bias1; M = M1; bid = blockIdx.x - nb0;
    }
    int lane = threadIdx.x & 63;
    int wave = threadIdx.x >> 6;
    int m_base = bid * 128 + wave * 32;
    int lm = lane & 15;      // A row-in-tile / C col-in-tile
    int kg = lane >> 4;      // k-group (8 consecutive k)

    int r0 = m_base + lm, r1 = r0 + 16;
    int cr0 = r0 < M ? r0 : M - 1;
    int cr1 = r1 < M ? r1 : M - 1;
    int row0 = aidx ? aidx[cr0] : cr0;
    int row1 = aidx ? aidx[cr1] : cr1;
    const ushort* bp = Wb + (size_t)lm * K + kg * 8;

    f32x4 acc[2][NT] = {};
    for (int k0 = 0; k0 < K; k0 += 32) {
        bf16x8 a[2];
        if (ABF) {
            const ushort* a0p = (const ushort*)A + (size_t)row0 * K + kg * 8;
            const ushort* a1p = (const ushort*)A + (size_t)row1 * K + kg * 8;
            a[0] = *reinterpret_cast<const bf16x8*>(a0p + k0);
            a[1] = *reinterpret_cast<const bf16x8*>(a1p + k0);
        } else {
            const float* a0p = (const float*)A + (size_t)row0 * K + kg * 8;
            const float* a1p = (const float*)A + (size_t)row1 * K + kg * 8;
            float af[2][8];
            *reinterpret_cast<float4*>(&af[0][0]) = *reinterpret_cast<const float4*>(a0p + k0);
            *reinterpret_cast<float4*>(&af[0][4]) = *reinterpret_cast<const float4*>(a0p + k0 + 4);
            *reinterpret_cast<float4*>(&af[1][0]) = *reinterpret_cast<const float4*>(a1p + k0);
            *reinterpret_cast<float4*>(&af[1][4]) = *reinterpret_cast<const float4*>(a1p + k0 + 4);
            #pragma unroll
            for (int mi = 0; mi < 2; ++mi)
                #pragma unroll
                for (int j = 0; j < 8; ++j) a[mi][j] = f2bf(af[mi][j]);
        }
        #pragma unroll
        for (int nt = 0; nt < NT; ++nt) {
            bf16x8 b = *reinterpret_cast<const bf16x8*>(bp + (size_t)nt * 16 * K + k0);
            acc[0][nt] = __builtin_amdgcn_mfma_f32_16x16x32_bf16(a[0], b, acc[0][nt], 0, 0, 0);
            acc[1][nt] = __builtin_amdgcn_mfma_f32_16x16x32_bf16(a[1], b, acc[1][nt], 0, 0, 0);
        }
    }
    #pragma unroll
    for (int mi = 0; mi < 2; ++mi) {
        int rowb = m_base + mi * 16 + kg * 4;
        if (MODE == 0) {
            #pragma unroll
            for (int nt = 0; nt < NT - 1; ++nt) {
                int col = nt * 16 + lm;
                #pragma unroll
                for (int r = 0; r < 4; ++r) {
                    int row = rowb + r;
                    if (row < M) hsb[(size_t)row * HC + col] = (ushort)f2bf(acc[mi][nt][r]);
                }
            }
            #pragma unroll
            for (int r = 0; r < 4; ++r) {
                int row = rowb + r;
                if (row < M) {
                    float v = acc[mi][NT - 1][r];
                    if (lm < 4) atts[(size_t)row * 4 + lm] = v;
                    else if (lm < 8) attd[(size_t)row * 4 + (lm - 4)] = v;
                }
            }
        } else if (MODE == 1) {
            #pragma unroll
            for (int nt = 0; nt < NT; ++nt) {
                int col = nt * 16 + lm;
                float bv = bias[col];
                #pragma unroll
                for (int r = 0; r < 4; ++r) {
                    int row = rowb + r;
                    if (row < M) C[(size_t)row * ldc + col] = acc[mi][nt][r] + bv;
                }
            }
        } else {   // MODE 3: bf16 out, bias + lrelu01
            #pragma unroll
            for (int nt = 0; nt < NT; ++nt) {
                int col = nt * 16 + lm;
                float bv = bias[col];
                #pragma unroll
                for (int r = 0; r < 4; ++r) {
                    int row = rowb + r;
                    if (row < M) {
                        float v = acc[mi][nt][r] + bv;
                        v = v > 0.f ? v : 0.01f * v;
                        hsb[(size_t)row * HC + col] = (ushort)f2bf(v);
                    }
                }
            }
        }
    }
}

// ---------------- CSR build (dual edge-type) --------------------------------
__global__ void hist_dual_k(const int* __restrict__ d0, int* __restrict__ c0, int E0,
                            const int* __restrict__ d1, int* __restrict__ c1, int E1,
                            int* __restrict__ rank) {
    int e = blockIdx.x * 256 + threadIdx.x;
    if (e < E0) rank[e] = atomicAdd(&c0[d0[e]], 1);
    else if (e - E0 < E1) rank[e] = atomicAdd(&c1[d1[e - E0]], 1);
}

__device__ __forceinline__ void scan_block_body(
    const int* deg, int n, int len, int* out, int* partial, int b) {
    __shared__ int s[256];
    int i = b * 256 + threadIdx.x;
    int v = (i < n) ? deg[i] : 0;
    s[threadIdx.x] = v;
    __syncthreads();
    for (int off = 1; off < 256; off <<= 1) {
        int t = (threadIdx.x >= off) ? s[threadIdx.x - off] : 0;
        __syncthreads();
        s[threadIdx.x] += t;
        __syncthreads();
    }
    if (i < len) out[i] = s[threadIdx.x] - v;
    if (threadIdx.x == 255) partial[b] = s[255];
}

__global__ void scan_block_dual_k(const int* dM, int nM, int* rsM, int* pM, int nbM,
                                  const int* dU, int nU, int* rsU, int* pU) {
    if ((int)blockIdx.x < nbM)
        scan_block_body(dM, nM, nM + 1, rsM, pM, blockIdx.x);
    else
        scan_block_body(dU, nU, nU + 1, rsU, pU, blockIdx.x - nbM);
}

__global__ void scan_partial_dual_k(int* pM, int nbM, int* pU, int nbU) {
    __shared__ int s[512];
    int t = threadIdx.x;
    for (int seg = 0; seg < 2; ++seg) {
        int* p = seg ? pU : pM;
        int nb = seg ? nbU : nbM;
        int v = (t < nb) ? p[t] : 0;
        s[t] = v;
        __syncthreads();
        for (int off = 1; off < 512; off <<= 1) {
            int x = (t >= off) ? s[t - off] : 0;
            __syncthreads();
            s[t] += x;
            __syncthreads();
        }
        if (t < nb) p[t] = s[t] - v;
        __syncthreads();
    }
}

__global__ void add_off_dual_k(int* __restrict__ oM, const int* __restrict__ pM,
                               int lenM, int nbM,
                               int* __restrict__ oU, const int* __restrict__ pU,
                               int lenU) {
    int b = blockIdx.x;
    if (b < nbM) {
        int i = b * 256 + threadIdx.x;
        if (i < lenM) oM[i] += pM[b];
    } else {
        b -= nbM;
        int i = b * 256 + threadIdx.x;
        if (i < lenU) oU[i] += pU[b];
    }
}

// atomic-free, dst-windowed scatter: window w handles dst in [w*n/NWIN, ...).
__global__ void fill_dual_k(const int* __restrict__ s0, const int* __restrict__ d0,
                            const int* __restrict__ rs0, int* __restrict__ csr0,
                            int E0, int n0,
                            const int* __restrict__ s1, const int* __restrict__ d1,
                            const int* __restrict__ rs1, int* __restrict__ csr1,
                            int E1, int n1,
                            const int* __restrict__ rank) {
    int e = blockIdx.x * 256 + threadIdx.x;
    int w = blockIdx.y;
    if (e < E0) {
        int d = d0[e];
        int lo = (int)((long)w * n0 / NWIN), hi = (int)((long)(w + 1) * n0 / NWIN);
        if (d >= lo && d < hi) csr0[rs0[d] + rank[e]] = s0[e];
    } else if (e - E0 < E1) {
        int e1 = e - E0;
        int d = d1[e1];
        int lo = (int)((long)w * n1 / NWIN), hi = (int)((long)(w + 1) * n1 / NWIN);
        if (d >= lo && d < hi) csr1[rs1[d] + rank[e]] = s1[e1];
    }
}

// ---------------- layer-2 per-dst aggregation: 32 lanes/node, 4-deep --------
template <bool WF32, bool WBF>
__global__ __launch_bounds__(256) void agg_dual_k(
    const int* __restrict__ rs0, const int* __restrict__ csr0,
    const ushort* __restrict__ hsb0, const float* __restrict__ atts0,
    const float* __restrict__ attd0, const float* __restrict__ bias0,
    float* __restrict__ out0, ushort* __restrict__ outb0, int n0,
    const int* __restrict__ rs1, const int* __restrict__ csr1,
    const ushort* __restrict__ hsb1, const float* __restrict__ atts1,
    const float* __restrict__ attd1, const float* __restrict__ bias1,
    float* __restrict__ out1, ushort* __restrict__ outb1, int n1) {
    int g = (int)((blockIdx.x * 256u + threadIdx.x) >> 5);
    const int* rs; const int* csr; const ushort* hsb; const float* atts;
    const float* attd; const float* bias; float* out; ushort* outb; int node;
    if (g < n0) {
        rs = rs0; csr = csr0; hsb = hsb0; atts = atts0; attd = attd0;
        bias = bias0; out = out0; outb = outb0; node = g;
    } else {
        node = g - n0;
        if (node >= n1) return;
        rs = rs1; csr = csr1; hsb = hsb1; atts = atts1; attd = attd1;
        bias = bias1; out = out1; outb = outb1;
    }
    int c = threadIdx.x & 31;    // channel group 4c..4c+3
    int h = c >> 3;              // head
    float ad = attd[node * 4 + h];
    int s0 = rs[node], s1 = rs[node + 1];
    float4 acc = make_float4(0.f, 0.f, 0.f, 0.f);
    float wsum = 0.f;
    int i = s0;
    for (; i + 4 <= s1; i += 4) {
        int sx[4];
        #pragma unroll
        for (int j = 0; j < 4; ++j) sx[j] = csr[i + j];
        ushort4 hv[4]; float el[4];
        #pragma unroll
        for (int j = 0; j < 4; ++j) {
            hv[j] = *reinterpret_cast<const ushort4*>(hsb + (size_t)sx[j] * HC + 4 * c);
            el[j] = atts[(size_t)sx[j] * 4 + h];
        }
        #pragma unroll
        for (int j = 0; j < 4; ++j) {
            float e = el[j] + ad;
            e = e > 0.f ? e : 0.2f * e;
            float w = __expf(e);
            wsum += w;
            acc.x = fmaf(w, bf2f(hv[j].x), acc.x);
            acc.y = fmaf(w, bf2f(hv[j].y), acc.y);
            acc.z = fmaf(w, bf2f(hv[j].z), acc.z);
            acc.w = fmaf(w, bf2f(hv[j].w), acc.w);
        }
    }
    for (; i < s1; ++i) {
        int src = csr[i];
        ushort4 hv = *reinterpret_cast<const ushort4*>(hsb + (size_t)src * HC + 4 * c);
        float e = atts[(size_t)src * 4 + h] + ad;
        e = e > 0.f ? e : 0.2f * e;
        float w = __expf(e);
        wsum += w;
        acc.x = fmaf(w, bf2f(hv.x), acc.x);
        acc.y = fmaf(w, bf2f(hv.y), acc.y);
        acc.z = fmaf(w, bf2f(hv.z), acc.z);
        acc.w = fmaf(w, bf2f(hv.w), acc.w);
    }
    float inv = 1.f / (wsum + 1e-16f);
    float4 b4 = reinterpret_cast<const float4*>(bias)[c];
    float4 v;
    v.x = fmaf(acc.x, inv, b4.x);
    v.y = fmaf(acc.y, inv, b4.y);
    v.z = fmaf(acc.z, inv, b4.z);
    v.w = fmaf(acc.w, inv, b4.w);
    v.x = v.x > 0.f ? v.x : 0.01f * v.x;
    v.y = v.y > 0.f ? v.y : 0.01f * v.y;
    v.z = v.z > 0.f ? v.z : 0.01f * v.z;
    v.w = v.w > 0.f ? v.w : 0.01f * v.w;
    if (WF32)
        reinterpret_cast<float4*>(out + (size_t)node * HC)[c] = v;
    if (WBF) {
        ushort4 vb;
        vb.x = (ushort)f2bf(v.x); vb.y = (ushort)f2bf(v.y);
        vb.z = (ushort)f2bf(v.z); vb.w = (ushort)f2bf(v.w);
        reinterpret_cast<ushort4*>(outb + (size_t)node * HC)[c] = vb;
    }
}

// ---------------------------------------------------------------------------
extern "C" void kernel_launch(void* const* d_in, const int* in_sizes, int n_in,
                              void* d_out, int out_size, void* d_ws, size_t ws_size,
                              hipStream_t stream) {
    const int Nu = in_sizes[0];
    const int Nm = in_sizes[1];
    const int E1 = in_sizes[2];   // um edges
    const int E2 = in_sizes[4];   // mu edges
    const int D  = in_sizes[6] / Nu;   // 64
    const int O  = in_sizes[27];       // 64

    const int*   user_ids  = (const int*)d_in[0];
    const int*   movie_ids = (const int*)d_in[1];
    const int*   um_src    = (const int*)d_in[2];
    const int*   um_dst    = (const int*)d_in[3];
    const int*   mu_src    = (const int*)d_in[4];
    const int*   mu_dst    = (const int*)d_in[5];
    const float* user_emb  = (const float*)d_in[6];
    const float* movie_emb = (const float*)d_in[7];
    const float* l1_um_Wsrc = (const float*)d_in[8];
    const float* l1_um_Wdst = (const float*)d_in[9];
    const float* l1_um_asrc = (const float*)d_in[10];
    const float* l1_um_adst = (const float*)d_in[11];
    const float* l1_um_b    = (const float*)d_in[12];
    const float* l1_mu_Wsrc = (const float*)d_in[13];
    const float* l1_mu_Wdst = (const float*)d_in[14];
    const float* l1_mu_asrc = (const float*)d_in[15];
    const float* l1_mu_adst = (const float*)d_in[16];
    const float* l1_mu_b    = (const float*)d_in[17];
    const float* l2_um_W    = (const float*)d_in[18];
    const float* l2_um_asrc = (const float*)d_in[19];
    const float* l2_um_adst = (const float*)d_in[20];
    const float* l2_um_b    = (const float*)d_in[21];
    const float* l2_mu_W    = (const float*)d_in[22];
    const float* l2_mu_asrc = (const float*)d_in[23];
    const float* l2_mu_adst = (const float*)d_in[24];
    const float* l2_mu_b    = (const float*)d_in[25];
    const float* Wo         = (const float*)d_in[26];
    const float* bo         = (const float*)d_in[27];

    // ---- workspace carve ----
    char* p = (char*)d_ws;
    auto alloc = [&](size_t bytes) { void* r = p; p += (bytes + 255) & ~(size_t)255; return r; };
    ushort* hs_u = (ushort*)alloc((size_t)Nu * HC * 2);
    ushort* hs_m = (ushort*)alloc((size_t)Nm * HC * 2);
    ushort* XUb  = (ushort*)alloc((size_t)Nu * HC * 2);
    ushort* XMb  = (ushort*)alloc((size_t)Nm * HC * 2);
    float* atts_u = (float*)alloc((size_t)Nu * 4 * 4);
    float* attd_u = (float*)alloc((size_t)Nu * 4 * 4);
    float* atts_m = (float*)alloc((size_t)Nm * 4 * 4);
    float* attd_m = (float*)alloc((size_t)Nm * 4 * 4);
    float* V_u1  = (float*)alloc((size_t)HC * 8 * 4);
    float* V_m1  = (float*)alloc((size_t)HC * 8 * 4);
    float* V_u2  = (float*)alloc((size_t)HC * 8 * 4);
    float* V_m2  = (float*)alloc((size_t)HC * 8 * 4);
    ushort* Wb_u1 = (ushort*)alloc((size_t)144 * D * 2);
    ushort* Wb_m1 = (ushort*)alloc((size_t)144 * D * 2);
    ushort* Wb_u2 = (ushort*)alloc((size_t)144 * HC * 2);
    ushort* Wb_m2 = (ushort*)alloc((size_t)144 * HC * 2);
    ushort* Wb_o  = (ushort*)alloc((size_t)64 * HC * 2);
    int* um_rs  = (int*)alloc((size_t)(Nm + 1) * 4);
    int* mu_rs  = (int*)alloc((size_t)(Nu + 1) * 4);
    int* cnts   = (int*)alloc((size_t)(Nm + Nu) * 4);   // um_cnt | mu_cnt
    int* um_cnt = cnts;
    int* mu_cnt = cnts + Nm;
    int* um_csr = (int*)alloc((size_t)E1 * 4);
    int* mu_csr = (int*)alloc((size_t)E2 * 4);
    int* rank   = (int*)alloc((size_t)(E1 + E2) * 4);
    int* partM  = (int*)alloc(512 * 4);
    int* partU  = (int*)alloc(512 * 4);

    // layer-1 temporaries alias hs_u/hs_m (dead until layer-2 GEMM writes them)
    ushort* XUe   = hs_u;                        // [Nu,64] bf16 features
    ushort* xaggU = hs_u + (size_t)Nu * 64;      // [Nu,64] bf16 weighted mean
    ushort* XMe   = hs_m;
    ushort* xaggM = hs_m + (size_t)Nm * 64;

    auto cdiv = [](int a, int b) { return (a + b - 1) / b; };

    // ---- fold attention + pack weights (x-independent) ----
    {
        VT vt;
        const float* Ws[8] = {l1_um_Wsrc, l1_mu_Wdst, l1_mu_Wsrc, l1_um_Wdst,
                              l2_um_W, l2_mu_W, l2_mu_W, l2_um_W};
        const float* as[8] = {l1_um_asrc, l1_mu_adst, l1_mu_asrc, l1_um_adst,
                              l2_um_asrc, l2_mu_adst, l2_mu_asrc, l2_um_adst};
        float* vs[8] = {V_u1, V_u1, V_m1, V_m1, V_u2, V_u2, V_m2, V_m2};
        for (int i = 0; i < 8; ++i) { vt.W[i] = Ws[i]; vt.a[i] = as[i]; vt.v[i] = vs[i]; }
        make_v_all_k<<<12, 256, 0, stream>>>(vt);

        PT pt;
        const float* pW[5] = {l1_um_Wsrc, l1_mu_Wsrc, l2_um_W, l2_mu_W, Wo};
        const float* pV[5] = {V_u1, V_m1, V_u2, V_m2, nullptr};
        ushort* pB[5] = {Wb_u1, Wb_m1, Wb_u2, Wb_m2, Wb_o};
        int pK[5] = {D, D, HC, HC, HC};
        int pN[5] = {HC, HC, HC, HC, 64};
        int cum = 0;
        for (int i = 0; i < 5; ++i) {
            pt.W[i] = pW[i]; pt.V[i] = pV[i]; pt.Wb[i] = pB[i];
            pt.K[i] = pK[i]; pt.Nw[i] = pN[i];
            pt.start[i] = cum;
            cum += (i < 4 ? 144 : 64) * pK[i];
        }
        pt.start[5] = cum;
        pack_all_k<<<cdiv(cum, 256), 256, 0, stream>>>(pt);
    }

    // ---- CSR build (both edge types, reused by both layers) ----
    int nbM = cdiv(Nm + 1, 256), nbU = cdiv(Nu + 1, 256);
    hipMemsetAsync(cnts, 0, (size_t)(Nm + Nu) * 4, stream);
    hist_dual_k<<<cdiv(E1 + E2, 256), 256, 0, stream>>>(
        um_dst, um_cnt, E1, mu_dst, mu_cnt, E2, rank);
    scan_block_dual_k<<<nbM + nbU, 256, 0, stream>>>(um_cnt, Nm, um_rs, partM, nbM,
                                                     mu_cnt, Nu, mu_rs, partU);
    scan_partial_dual_k<<<1, 512, 0, stream>>>(partM, nbM, partU, nbU);
    add_off_dual_k<<<nbM + nbU, 256, 0, stream>>>(um_rs, partM, Nm + 1, nbM,
                                                  mu_rs, partU, Nu + 1);
    {
        dim3 g(cdiv(E1 + E2, 256), NWIN);
        fill_dual_k<<<g, 256, 0, stream>>>(
            um_src, um_dst, um_rs, um_csr, E1, Nm,
            mu_src, mu_dst, mu_rs, mu_csr, E2, Nu, rank);
    }

    // output slots: [out_user | out_movie | xu | xm]
    float* OU = (float*)d_out;
    float* OM = OU + (size_t)Nu * O;
    float* XU = OM + (size_t)Nm * O;
    float* XM = XU + (size_t)Nu * HC;

    int gbU = cdiv(Nu, 128), gbM = cdiv(Nm, 128);

    // ---- layer 1: convert+att -> weighted-mean gather -> transform GEMM ----
    conv_att_dual_k<<<cdiv((Nu + Nm) * 16, 256), 256, 0, stream>>>(
        user_emb, user_ids, V_u1, XUe, atts_u, attd_u, Nu,
        movie_emb, movie_ids, V_m1, XMe, atts_m, attd_m, Nm);
    aggm_dual_k<<<cdiv((Nm + Nu) * 16, 256), 256, 0, stream>>>(
        um_rs, um_csr, XUe, atts_u, attd_m, xaggM, Nm,
        mu_rs, mu_csr, XMe, atts_m, attd_u, xaggU, Nu);
    gemm_dual_k<8, 3, true><<<gbM + gbU, 256, 0, stream>>>(
        xaggM, nullptr, Wb_u1, XMb, nullptr, nullptr, nullptr, l1_um_b, Nm, gbM,
        xaggU, nullptr, Wb_m1, XUb, nullptr, nullptr, nullptr, l1_mu_b, Nu,
        D, 0);

    // ---- layer 2: A = bf16 activations, K = HC ----
    gemm_dual_k<9, 0, true><<<gbU + gbM, 256, 0, stream>>>(
        XUb, nullptr, Wb_u2, hs_u, atts_u, attd_u, nullptr, nullptr, Nu, gbU,
        XMb, nullptr, Wb_m2, hs_m, atts_m, attd_m, nullptr, nullptr, Nm,
        HC, 0);
    int aggBlocks = cdiv((Nm + Nu) * 32, 256);
    agg_dual_k<true, false><<<aggBlocks, 256, 0, stream>>>(
        um_rs, um_csr, hs_u, atts_u, attd_m, l2_um_b, XM, nullptr, Nm,
        mu_rs, mu_csr, hs_m, atts_m, attd_u, l2_mu_b, XU, nullptr, Nu);

    // ---- final projection: out = x @ Wo + bo (fp32 A) ----
    gemm_dual_k<4, 1, false><<<gbU + gbM, 256, 0, stream>>>(
        XU, nullptr, Wb_o, nullptr, nullptr, nullptr, OU, bo, Nu, gbU,
        XM, nullptr, Wb_o, nullptr, nullptr, nullptr, OM, bo, Nm,
        HC, O);
}

// Round 8
// 247.750 us; speedup vs baseline: 2.8264x; 1.0927x over previous
//
#include <hip/hip_runtime.h>
#include <hip/hip_bf16.h>
#include <cstdint>

// ---------------------------------------------------------------------------
// HGAT: 2-layer hetero GAT (user<->movie), H=4 heads, C=32, HC=128.
// GEMMs on bf16 MFMA 16x16x32, fp32 accumulate; folded attention matrix V
// appended to packed weights so hs+att come out of one GEMM (MODE 0).
// Edge aggregation: CSR by dst, **16 lanes/node, ushort8 (16B) loads** --
// one wave-wide VMEM op covers 4 edge-rows (1KB), halving VMEM instructions
// per edge vs 32-lane layout (agg is latency/instruction-bound: 41% HBM,
// 51% VALU at 32-lane). Redundant per-edge exp work also halves.
// CSR build: rank-from-hist (atomic-free fill), dst-windowed scatter.
// Softmax max-subtraction skipped (logits bounded; shift-invariant; validated).
// ---------------------------------------------------------------------------

#define HC 128
#define HH 4
#define NWIN 4   // fill scatter windows

typedef __attribute__((ext_vector_type(8))) short bf16x8;
typedef __attribute__((ext_vector_type(4))) float f32x4;

__device__ __forceinline__ short f2bf(float f) {
    return __builtin_bit_cast(short, __float2bfloat16(f));
}
__device__ __forceinline__ float bf2f(ushort u) {
    return __builtin_bit_cast(float, ((unsigned)u) << 16);
}

// ---------------- fold attention: v[k, coff+h] = sum_c W[k,h*32+c]*a[h,c] ---
struct VT { const float* W[8]; const float* a[8]; float* v[8]; };
__global__ void make_v_all_k(VT t) {
    int gid = blockIdx.x * 256 + threadIdx.x;
    int task, base;
    if (gid < 1024) { task = gid >> 8; base = gid & 255; }
    else if (gid < 3072) { int g = gid - 1024; task = 4 + (g >> 9); base = g & 511; }
    else return;
    int k = base >> 2, h = base & 3;
    int coff = (task & 1) * 4;
    const float* wr = t.W[task] + (size_t)k * HC + h * 32;
    const float* ar = t.a[task] + h * 32;
    float s = 0.f;
    #pragma unroll
    for (int c = 0; c < 32; ++c) s = fmaf(wr[c], ar[c], s);
    t.v[task][k * 8 + coff + h] = s;
}

// ---------------- pack Wb[n][k] = bf16(W[k][n]); rows Nw..Nw+7 = V ----------
struct PT { const float* W[5]; const float* V[5]; ushort* Wb[5];
            int K[5]; int Nw[5]; int start[6]; };
__global__ void pack_all_k(PT t) {
    int gid = blockIdx.x * 256 + threadIdx.x;
    if (gid >= t.start[5]) return;
    int task = 0;
    while (gid >= t.start[task + 1]) ++task;
    int loc = gid - t.start[task];
    int K = t.K[task], Nw = t.Nw[task];
    int n = loc / K, k = loc % K;
    float v = 0.f;
    if (n < Nw) v = t.W[task][(size_t)k * Nw + n];
    else if (t.V[task] != nullptr && n < Nw + 8) v = t.V[task][k * 8 + (n - Nw)];
    t.Wb[task][loc] = (ushort)f2bf(v);
}

// ---------------- dual-segment bf16 MFMA GEMM -------------------------------
// MODE 0: hs out (bf16 [M,128]) + atts fp32 [M,4] + attd fp32 [M,4].
// MODE 1: fp32 C[M,ldc] + bias. ABF: A dense bf16 (ushort), else fp32 (+idx).
template <int NT, int MODE, bool ABF>
__global__ __launch_bounds__(256) void gemm_dual_k(
    const void* A0, const int* idx0, const ushort* Wb0, ushort* hsb0,
    float* atts0, float* attd0, float* C0, const float* bias0, int M0, int nb0,
    const void* A1, const int* idx1, const ushort* Wb1, ushort* hsb1,
    float* atts1, float* attd1, float* C1, const float* bias1, int M1,
    int K, int ldc) {
    const void* A; const int* aidx; const ushort* Wb; ushort* hsb;
    float* atts; float* attd; float* C; const float* bias; int M, bid;
    if ((int)blockIdx.x < nb0) {
        A = A0; aidx = idx0; Wb = Wb0; hsb = hsb0; atts = atts0; attd = attd0;
        C = C0; bias = bias0; M = M0; bid = blockIdx.x;
    } else {
        A = A1; aidx = idx1; Wb = Wb1; hsb = hsb1; atts = atts1; attd = attd1;
        C = C1; bias = bias1; M = M1; bid = blockIdx.x - nb0;
    }
    int lane = threadIdx.x & 63;
    int wave = threadIdx.x >> 6;
    int m_base = bid * 128 + wave * 32;
    int lm = lane & 15;      // A row-in-tile / C col-in-tile
    int kg = lane >> 4;      // k-group (8 consecutive k)

    int r0 = m_base + lm, r1 = r0 + 16;
    int cr0 = r0 < M ? r0 : M - 1;
    int cr1 = r1 < M ? r1 : M - 1;
    int row0 = aidx ? aidx[cr0] : cr0;
    int row1 = aidx ? aidx[cr1] : cr1;
    const ushort* bp = Wb + (size_t)lm * K + kg * 8;

    f32x4 acc[2][NT] = {};
    for (int k0 = 0; k0 < K; k0 += 32) {
        bf16x8 a[2];
        if (ABF) {
            const ushort* a0p = (const ushort*)A + (size_t)row0 * K + kg * 8;
            const ushort* a1p = (const ushort*)A + (size_t)row1 * K + kg * 8;
            a[0] = *reinterpret_cast<const bf16x8*>(a0p + k0);
            a[1] = *reinterpret_cast<const bf16x8*>(a1p + k0);
        } else {
            const float* a0p = (const float*)A + (size_t)row0 * K + kg * 8;
            const float* a1p = (const float*)A + (size_t)row1 * K + kg * 8;
            float af[2][8];
            *reinterpret_cast<float4*>(&af[0][0]) = *reinterpret_cast<const float4*>(a0p + k0);
            *reinterpret_cast<float4*>(&af[0][4]) = *reinterpret_cast<const float4*>(a0p + k0 + 4);
            *reinterpret_cast<float4*>(&af[1][0]) = *reinterpret_cast<const float4*>(a1p + k0);
            *reinterpret_cast<float4*>(&af[1][4]) = *reinterpret_cast<const float4*>(a1p + k0 + 4);
            #pragma unroll
            for (int mi = 0; mi < 2; ++mi)
                #pragma unroll
                for (int j = 0; j < 8; ++j) a[mi][j] = f2bf(af[mi][j]);
        }
        #pragma unroll
        for (int nt = 0; nt < NT; ++nt) {
            bf16x8 b = *reinterpret_cast<const bf16x8*>(bp + (size_t)nt * 16 * K + k0);
            acc[0][nt] = __builtin_amdgcn_mfma_f32_16x16x32_bf16(a[0], b, acc[0][nt], 0, 0, 0);
            acc[1][nt] = __builtin_amdgcn_mfma_f32_16x16x32_bf16(a[1], b, acc[1][nt], 0, 0, 0);
        }
    }
    #pragma unroll
    for (int mi = 0; mi < 2; ++mi) {
        int rowb = m_base + mi * 16 + kg * 4;
        if (MODE == 0) {
            #pragma unroll
            for (int nt = 0; nt < NT - 1; ++nt) {
                int col = nt * 16 + lm;
                #pragma unroll
                for (int r = 0; r < 4; ++r) {
                    int row = rowb + r;
                    if (row < M) hsb[(size_t)row * HC + col] = (ushort)f2bf(acc[mi][nt][r]);
                }
            }
            #pragma unroll
            for (int r = 0; r < 4; ++r) {
                int row = rowb + r;
                if (row < M) {
                    float v = acc[mi][NT - 1][r];
                    if (lm < 4) atts[(size_t)row * 4 + lm] = v;
                    else if (lm < 8) attd[(size_t)row * 4 + (lm - 4)] = v;
                }
            }
        } else {
            #pragma unroll
            for (int nt = 0; nt < NT; ++nt) {
                int col = nt * 16 + lm;
                float bv = bias[col];
                #pragma unroll
                for (int r = 0; r < 4; ++r) {
                    int row = rowb + r;
                    if (row < M) C[(size_t)row * ldc + col] = acc[mi][nt][r] + bv;
                }
            }
        }
    }
}

// ---------------- CSR build (dual edge-type) --------------------------------
__global__ void hist_dual_k(const int* __restrict__ d0, int* __restrict__ c0, int E0,
                            const int* __restrict__ d1, int* __restrict__ c1, int E1,
                            int* __restrict__ rank) {
    int e = blockIdx.x * 256 + threadIdx.x;
    if (e < E0) rank[e] = atomicAdd(&c0[d0[e]], 1);
    else if (e - E0 < E1) rank[e] = atomicAdd(&c1[d1[e - E0]], 1);
}

__device__ __forceinline__ void scan_block_body(
    const int* deg, int n, int len, int* out, int* partial, int b) {
    __shared__ int s[256];
    int i = b * 256 + threadIdx.x;
    int v = (i < n) ? deg[i] : 0;
    s[threadIdx.x] = v;
    __syncthreads();
    for (int off = 1; off < 256; off <<= 1) {
        int t = (threadIdx.x >= off) ? s[threadIdx.x - off] : 0;
        __syncthreads();
        s[threadIdx.x] += t;
        __syncthreads();
    }
    if (i < len) out[i] = s[threadIdx.x] - v;
    if (threadIdx.x == 255) partial[b] = s[255];
}

__global__ void scan_block_dual_k(const int* dM, int nM, int* rsM, int* pM, int nbM,
                                  const int* dU, int nU, int* rsU, int* pU) {
    if ((int)blockIdx.x < nbM)
        scan_block_body(dM, nM, nM + 1, rsM, pM, blockIdx.x);
    else
        scan_block_body(dU, nU, nU + 1, rsU, pU, blockIdx.x - nbM);
}

__global__ void scan_partial_dual_k(int* pM, int nbM, int* pU, int nbU) {
    __shared__ int s[512];
    int t = threadIdx.x;
    for (int seg = 0; seg < 2; ++seg) {
        int* p = seg ? pU : pM;
        int nb = seg ? nbU : nbM;
        int v = (t < nb) ? p[t] : 0;
        s[t] = v;
        __syncthreads();
        for (int off = 1; off < 512; off <<= 1) {
            int x = (t >= off) ? s[t - off] : 0;
            __syncthreads();
            s[t] += x;
            __syncthreads();
        }
        if (t < nb) p[t] = s[t] - v;
        __syncthreads();
    }
}

__global__ void add_off_dual_k(int* __restrict__ oM, const int* __restrict__ pM,
                               int lenM, int nbM,
                               int* __restrict__ oU, const int* __restrict__ pU,
                               int lenU) {
    int b = blockIdx.x;
    if (b < nbM) {
        int i = b * 256 + threadIdx.x;
        if (i < lenM) oM[i] += pM[b];
    } else {
        b -= nbM;
        int i = b * 256 + threadIdx.x;
        if (i < lenU) oU[i] += pU[b];
    }
}

// atomic-free, dst-windowed scatter: window w handles dst in [w*n/NWIN, ...).
__global__ void fill_dual_k(const int* __restrict__ s0, const int* __restrict__ d0,
                            const int* __restrict__ rs0, int* __restrict__ csr0,
                            int E0, int n0,
                            const int* __restrict__ s1, const int* __restrict__ d1,
                            const int* __restrict__ rs1, int* __restrict__ csr1,
                            int E1, int n1,
                            const int* __restrict__ rank) {
    int e = blockIdx.x * 256 + threadIdx.x;
    int w = blockIdx.y;
    if (e < E0) {
        int d = d0[e];
        int lo = (int)((long)w * n0 / NWIN), hi = (int)((long)(w + 1) * n0 / NWIN);
        if (d >= lo && d < hi) csr0[rs0[d] + rank[e]] = s0[e];
    } else if (e - E0 < E1) {
        int e1 = e - E0;
        int d = d1[e1];
        int lo = (int)((long)w * n1 / NWIN), hi = (int)((long)(w + 1) * n1 / NWIN);
        if (d >= lo && d < hi) csr1[rs1[d] + rank[e]] = s1[e1];
    }
}

// ---------------- per-dst aggregation: 16 lanes/node, ushort8 loads ---------
// Lane c in [0,16): channels 8c..8c+7 (16B load); head h = c>>2.
// One wave-wide VMEM op covers 4 edge-rows (1KB) -> half the VMEM instrs/edge
// vs 32-lane layout. bias + lrelu01 fused. WF32: fp32 out; WBF: bf16 out.
template <bool WF32, bool WBF>
__global__ __launch_bounds__(256) void agg16_dual_k(
    const int* __restrict__ rs0, const int* __restrict__ csr0,
    const ushort* __restrict__ hsb0, const float* __restrict__ atts0,
    const float* __restrict__ attd0, const float* __restrict__ bias0,
    float* __restrict__ out0, ushort* __restrict__ outb0, int n0,
    const int* __restrict__ rs1, const int* __restrict__ csr1,
    const ushort* __restrict__ hsb1, const float* __restrict__ atts1,
    const float* __restrict__ attd1, const float* __restrict__ bias1,
    float* __restrict__ out1, ushort* __restrict__ outb1, int n1) {
    int g = (int)((blockIdx.x * 256u + threadIdx.x) >> 4);   // 16 nodes/block
    const int* rs; const int* csr; const ushort* hsb; const float* atts;
    const float* attd; const float* bias; float* out; ushort* outb; int node;
    if (g < n0) {
        rs = rs0; csr = csr0; hsb = hsb0; atts = atts0; attd = attd0;
        bias = bias0; out = out0; outb = outb0; node = g;
    } else {
        node = g - n0;
        if (node >= n1) return;
        rs = rs1; csr = csr1; hsb = hsb1; atts = atts1; attd = attd1;
        bias = bias1; out = out1; outb = outb1;
    }
    int c = threadIdx.x & 15;    // channels 8c..8c+7
    int h = c >> 2;              // head (32 ch per head, 4 lanes per head)
    float ad = attd[node * 4 + h];
    int s0 = rs[node], s1 = rs[node + 1];
    float acc[8] = {};
    float wsum = 0.f;
    int i = s0;
    for (; i + 4 <= s1; i += 4) {            // 4 edge-rows in flight
        int sx[4];
        #pragma unroll
        for (int j = 0; j < 4; ++j) sx[j] = csr[i + j];
        bf16x8 hv[4]; float el[4];
        #pragma unroll
        for (int j = 0; j < 4; ++j) {
            hv[j] = *reinterpret_cast<const bf16x8*>(hsb + (size_t)sx[j] * HC + 8 * c);
            el[j] = atts[(size_t)sx[j] * 4 + h];
        }
        #pragma unroll
        for (int j = 0; j < 4; ++j) {
            float e = el[j] + ad;
            e = e > 0.f ? e : 0.2f * e;
            float w = __expf(e);
            wsum += w;
            #pragma unroll
            for (int k = 0; k < 8; ++k)
                acc[k] = fmaf(w, bf2f((ushort)hv[j][k]), acc[k]);
        }
    }
    for (; i < s1; ++i) {
        int src = csr[i];
        bf16x8 hv = *reinterpret_cast<const bf16x8*>(hsb + (size_t)src * HC + 8 * c);
        float e = atts[(size_t)src * 4 + h] + ad;
        e = e > 0.f ? e : 0.2f * e;
        float w = __expf(e);
        wsum += w;
        #pragma unroll
        for (int k = 0; k < 8; ++k)
            acc[k] = fmaf(w, bf2f((ushort)hv[k]), acc[k]);
    }
    float inv = 1.f / (wsum + 1e-16f);
    float v[8];
    #pragma unroll
    for (int k = 0; k < 8; ++k) {
        v[k] = fmaf(acc[k], inv, bias[8 * c + k]);
        v[k] = v[k] > 0.f ? v[k] : 0.01f * v[k];
    }
    if (WF32) {
        float4 o0 = make_float4(v[0], v[1], v[2], v[3]);
        float4 o1 = make_float4(v[4], v[5], v[6], v[7]);
        reinterpret_cast<float4*>(out + (size_t)node * HC + 8 * c)[0] = o0;
        reinterpret_cast<float4*>(out + (size_t)node * HC + 8 * c)[1] = o1;
    }
    if (WBF) {
        bf16x8 u;
        #pragma unroll
        for (int k = 0; k < 8; ++k) u[k] = f2bf(v[k]);
        *reinterpret_cast<bf16x8*>(outb + (size_t)node * HC + 8 * c) = u;
    }
}

// ---------------------------------------------------------------------------
extern "C" void kernel_launch(void* const* d_in, const int* in_sizes, int n_in,
                              void* d_out, int out_size, void* d_ws, size_t ws_size,
                              hipStream_t stream) {
    const int Nu = in_sizes[0];
    const int Nm = in_sizes[1];
    const int E1 = in_sizes[2];   // um edges
    const int E2 = in_sizes[4];   // mu edges
    const int D  = in_sizes[6] / Nu;   // 64
    const int O  = in_sizes[27];       // 64

    const int*   user_ids  = (const int*)d_in[0];
    const int*   movie_ids = (const int*)d_in[1];
    const int*   um_src    = (const int*)d_in[2];
    const int*   um_dst    = (const int*)d_in[3];
    const int*   mu_src    = (const int*)d_in[4];
    const int*   mu_dst    = (const int*)d_in[5];
    const float* user_emb  = (const float*)d_in[6];
    const float* movie_emb = (const float*)d_in[7];
    const float* l1_um_Wsrc = (const float*)d_in[8];
    const float* l1_um_Wdst = (const float*)d_in[9];
    const float* l1_um_asrc = (const float*)d_in[10];
    const float* l1_um_adst = (const float*)d_in[11];
    const float* l1_um_b    = (const float*)d_in[12];
    const float* l1_mu_Wsrc = (const float*)d_in[13];
    const float* l1_mu_Wdst = (const float*)d_in[14];
    const float* l1_mu_asrc = (const float*)d_in[15];
    const float* l1_mu_adst = (const float*)d_in[16];
    const float* l1_mu_b    = (const float*)d_in[17];
    const float* l2_um_W    = (const float*)d_in[18];
    const float* l2_um_asrc = (const float*)d_in[19];
    const float* l2_um_adst = (const float*)d_in[20];
    const float* l2_um_b    = (const float*)d_in[21];
    const float* l2_mu_W    = (const float*)d_in[22];
    const float* l2_mu_asrc = (const float*)d_in[23];
    const float* l2_mu_adst = (const float*)d_in[24];
    const float* l2_mu_b    = (const float*)d_in[25];
    const float* Wo         = (const float*)d_in[26];
    const float* bo         = (const float*)d_in[27];

    // ---- workspace carve ----
    char* p = (char*)d_ws;
    auto alloc = [&](size_t bytes) { void* r = p; p += (bytes + 255) & ~(size_t)255; return r; };
    ushort* hs_u = (ushort*)alloc((size_t)Nu * HC * 2);
    ushort* hs_m = (ushort*)alloc((size_t)Nm * HC * 2);
    ushort* XUb  = (ushort*)alloc((size_t)Nu * HC * 2);
    ushort* XMb  = (ushort*)alloc((size_t)Nm * HC * 2);
    float* atts_u = (float*)alloc((size_t)Nu * 4 * 4);
    float* attd_u = (float*)alloc((size_t)Nu * 4 * 4);
    float* atts_m = (float*)alloc((size_t)Nm * 4 * 4);
    float* attd_m = (float*)alloc((size_t)Nm * 4 * 4);
    float* V_u1  = (float*)alloc((size_t)HC * 8 * 4);
    float* V_m1  = (float*)alloc((size_t)HC * 8 * 4);
    float* V_u2  = (float*)alloc((size_t)HC * 8 * 4);
    float* V_m2  = (float*)alloc((size_t)HC * 8 * 4);
    ushort* Wb_u1 = (ushort*)alloc((size_t)144 * D * 2);
    ushort* Wb_m1 = (ushort*)alloc((size_t)144 * D * 2);
    ushort* Wb_u2 = (ushort*)alloc((size_t)144 * HC * 2);
    ushort* Wb_m2 = (ushort*)alloc((size_t)144 * HC * 2);
    ushort* Wb_o  = (ushort*)alloc((size_t)64 * HC * 2);
    int* um_rs  = (int*)alloc((size_t)(Nm + 1) * 4);
    int* mu_rs  = (int*)alloc((size_t)(Nu + 1) * 4);
    int* cnts   = (int*)alloc((size_t)(Nm + Nu) * 4);   // um_cnt | mu_cnt
    int* um_cnt = cnts;
    int* mu_cnt = cnts + Nm;
    int* um_csr = (int*)alloc((size_t)E1 * 4);
    int* mu_csr = (int*)alloc((size_t)E2 * 4);
    int* rank   = (int*)alloc((size_t)(E1 + E2) * 4);
    int* partM  = (int*)alloc(512 * 4);
    int* partU  = (int*)alloc(512 * 4);

    auto cdiv = [](int a, int b) { return (a + b - 1) / b; };

    // ---- fold attention + pack weights (x-independent) ----
    {
        VT vt;
        const float* Ws[8] = {l1_um_Wsrc, l1_mu_Wdst, l1_mu_Wsrc, l1_um_Wdst,
                              l2_um_W, l2_mu_W, l2_mu_W, l2_um_W};
        const float* as[8] = {l1_um_asrc, l1_mu_adst, l1_mu_asrc, l1_um_adst,
                              l2_um_asrc, l2_mu_adst, l2_mu_asrc, l2_um_adst};
        float* vs[8] = {V_u1, V_u1, V_m1, V_m1, V_u2, V_u2, V_m2, V_m2};
        for (int i = 0; i < 8; ++i) { vt.W[i] = Ws[i]; vt.a[i] = as[i]; vt.v[i] = vs[i]; }
        make_v_all_k<<<12, 256, 0, stream>>>(vt);

        PT pt;
        const float* pW[5] = {l1_um_Wsrc, l1_mu_Wsrc, l2_um_W, l2_mu_W, Wo};
        const float* pV[5] = {V_u1, V_m1, V_u2, V_m2, nullptr};
        ushort* pB[5] = {Wb_u1, Wb_m1, Wb_u2, Wb_m2, Wb_o};
        int pK[5] = {D, D, HC, HC, HC};
        int pN[5] = {HC, HC, HC, HC, 64};
        int cum = 0;
        for (int i = 0; i < 5; ++i) {
            pt.W[i] = pW[i]; pt.V[i] = pV[i]; pt.Wb[i] = pB[i];
            pt.K[i] = pK[i]; pt.Nw[i] = pN[i];
            pt.start[i] = cum;
            cum += (i < 4 ? 144 : 64) * pK[i];
        }
        pt.start[5] = cum;
        pack_all_k<<<cdiv(cum, 256), 256, 0, stream>>>(pt);
    }

    // ---- CSR build (both edge types, reused by both layers) ----
    int nbM = cdiv(Nm + 1, 256), nbU = cdiv(Nu + 1, 256);
    hipMemsetAsync(cnts, 0, (size_t)(Nm + Nu) * 4, stream);
    hist_dual_k<<<cdiv(E1 + E2, 256), 256, 0, stream>>>(
        um_dst, um_cnt, E1, mu_dst, mu_cnt, E2, rank);
    scan_block_dual_k<<<nbM + nbU, 256, 0, stream>>>(um_cnt, Nm, um_rs, partM, nbM,
                                                     mu_cnt, Nu, mu_rs, partU);
    scan_partial_dual_k<<<1, 512, 0, stream>>>(partM, nbM, partU, nbU);
    add_off_dual_k<<<nbM + nbU, 256, 0, stream>>>(um_rs, partM, Nm + 1, nbM,
                                                  mu_rs, partU, Nu + 1);
    {
        dim3 g(cdiv(E1 + E2, 256), NWIN);
        fill_dual_k<<<g, 256, 0, stream>>>(
            um_src, um_dst, um_rs, um_csr, E1, Nm,
            mu_src, mu_dst, mu_rs, mu_csr, E2, Nu, rank);
    }

    // output slots: [out_user | out_movie | xu | xm]
    float* OU = (float*)d_out;
    float* OM = OU + (size_t)Nu * O;
    float* XU = OM + (size_t)Nm * O;
    float* XM = XU + (size_t)Nu * HC;

    int gbU = cdiv(Nu, 128), gbM = cdiv(Nm, 128);
    int aggBlocks = cdiv((Nm + Nu) * 16, 256);

    // ---- layer 1: A = fp32 embeddings (gathered), K = D ----
    gemm_dual_k<9, 0, false><<<gbU + gbM, 256, 0, stream>>>(
        user_emb, user_ids, Wb_u1, hs_u, atts_u, attd_u, nullptr, nullptr, Nu, gbU,
        movie_emb, movie_ids, Wb_m1, hs_m, atts_m, attd_m, nullptr, nullptr, Nm,
        D, 0);
    // layer-1 agg: bf16 activations only (fp32 slot would be overwritten by L2)
    agg16_dual_k<false, true><<<aggBlocks, 256, 0, stream>>>(
        um_rs, um_csr, hs_u, atts_u, attd_m, l1_um_b, nullptr, XMb, Nm,
        mu_rs, mu_csr, hs_m, atts_m, attd_u, l1_mu_b, nullptr, XUb, Nu);

    // ---- layer 2: A = bf16 activations, K = HC ----
    gemm_dual_k<9, 0, true><<<gbU + gbM, 256, 0, stream>>>(
        XUb, nullptr, Wb_u2, hs_u, atts_u, attd_u, nullptr, nullptr, Nu, gbU,
        XMb, nullptr, Wb_m2, hs_m, atts_m, attd_m, nullptr, nullptr, Nm,
        HC, 0);
    // layer-2 agg: fp32 only (xu/xm are outputs; proj reads fp32)
    agg16_dual_k<true, false><<<aggBlocks, 256, 0, stream>>>(
        um_rs, um_csr, hs_u, atts_u, attd_m, l2_um_b, XM, nullptr, Nm,
        mu_rs, mu_csr, hs_m, atts_m, attd_u, l2_mu_b, XU, nullptr, Nu);

    // ---- final projection: out = x @ Wo + bo (fp32 A) ----
    gemm_dual_k<4, 1, false><<<gbU + gbM, 256, 0, stream>>>(
        XU, nullptr, Wb_o, nullptr, nullptr, nullptr, OU, bo, Nu, gbU,
        XM, nullptr, Wb_o, nullptr, nullptr, nullptr, OM, bo, Nm,
        HC, O);
}